// Round 3
// baseline (322.424 us; speedup 1.0000x reference)
//
#include <hip/hip_runtime.h>
#include <hip/hip_bf16.h>
#include <stdint.h>

// MultiHeadAttention: B=2, S=2048, D_MODEL=1024, H=16, depth=64.
// Reference is float32; harness MAY have converted tensors to bf16.
// We detect the float dtype at runtime (probe kernel) and handle both.
//
// Pipeline (all on `stream`):
//   0) probe: detect bf16 (flag=1) vs f32 (flag=0) from q's bit patterns
//   1) prep_qkv: if f32, convert q,k,v -> bf16 buffers (skip if bf16)
//   2) prep_w:   transpose wq,wk,wv,wo -> bf16 W^T   (dual-dtype read)
//   3) prep_bias: biases -> bf16                      (dual-dtype read)
//   4) gemm_bt (z=3): Q/K/V projections -> Qh[b,h,s,d], Kh[b,h,s,d], Vt[b,h,d,s]
//   5) attn: flash attention, 64 q-rows/block, online softmax (exp2 domain)
//   6) gemm_bt (mode 0): Oh @ wo^T + bo -> out (bf16 or f32 per flag)

typedef __bf16 bf16;
typedef __bf16 bf16x8 __attribute__((ext_vector_type(8)));
typedef __bf16 bf16x4 __attribute__((ext_vector_type(4)));
typedef float  f32x4  __attribute__((ext_vector_type(4)));

#define D_MODEL 1024
#define S_LEN   2048
#define NH      16
#define DEPTH   64

#define LOG2E    1.4426950408889634f
#define MASK_PEN (-30000.0f)   // log2-domain additive penalty; cancels in softmax

__device__ __forceinline__ void gload_lds16(const void* g, void* l) {
  __builtin_amdgcn_global_load_lds(
      (__attribute__((address_space(1))) void*)g,
      (__attribute__((address_space(3))) void*)l,
      16, 0, 0);
}

__device__ __forceinline__ float scrub(float x, float rep) {
  // diagnostic: replace non-finite/huge with a stage signature (no-op when correct)
  return (x == x && fabsf(x) < 1e30f) ? x : rep;
}

// ---------------------------------------------------------------- dtype probe
// bf16 data: word bits[14:7] = low-half bf16 exponent, ~always in [90,150].
// f32 data:  bits[14:7] = mantissa tail, ~uniform -> ~24% in range.
__global__ void probe_dtype(const uint32_t* __restrict__ qw, int* __restrict__ flag)
{
  const int t = threadIdx.x;  // 64 threads
  int c = 0;
  for (int i = 0; i < 4; ++i) {
    uint32_t w = qw[t * 4 + i];
    uint32_t e = (w >> 7) & 0xFF;
    c += (e >= 90 && e <= 150) ? 1 : 0;
  }
  for (int s = 1; s < 64; s <<= 1) c += __shfl_xor(c, s);
  if (t == 0) *flag = (c > 160) ? 1 : 0;
}

// ---------------------------------------------------------------- conversion
__global__ __launch_bounds__(256) void prep_qkv(
    const void* __restrict__ q, const void* __restrict__ k,
    const void* __restrict__ v,
    bf16* __restrict__ qb, bf16* __restrict__ kb, bf16* __restrict__ vb,
    const int* __restrict__ flagp)
{
  if (*flagp) return;  // already bf16: gemm reads the raw pointers
  const void* src; bf16* dst;
  switch (blockIdx.z) {
    case 0:  src = q; dst = qb; break;
    case 1:  src = k; dst = kb; break;
    default: src = v; dst = vb; break;
  }
  const size_t idx = ((size_t)blockIdx.x * 256 + threadIdx.x) * 8;
  const float* s = (const float*)src + idx;
  f32x4 a = *(const f32x4*)(s);
  f32x4 b = *(const f32x4*)(s + 4);
  bf16x8 o;
  for (int i = 0; i < 4; ++i) { o[i] = (bf16)a[i]; o[4 + i] = (bf16)b[i]; }
  *(bf16x8*)(dst + idx) = o;
}

__global__ __launch_bounds__(256) void prep_w(
    const void* __restrict__ w0, const void* __restrict__ w1,
    const void* __restrict__ w2, const void* __restrict__ w3,
    bf16* __restrict__ t0, bf16* __restrict__ t1,
    bf16* __restrict__ t2, bf16* __restrict__ t3,
    const int* __restrict__ flagp)
{
  const int flag = *flagp;
  const void* W; bf16* T;
  switch (blockIdx.z) {
    case 0:  W = w0; T = t0; break;
    case 1:  W = w1; T = t1; break;
    case 2:  W = w2; T = t2; break;
    default: W = w3; T = t3; break;
  }
  __shared__ float tile[32][33];
  const int tx = threadIdx.x;            // 0..31
  const int x0 = blockIdx.x * 32;        // col
  const int y0 = blockIdx.y * 32;        // row
  for (int i = threadIdx.y; i < 32; i += 8) {
    const size_t gi = (size_t)(y0 + i) * D_MODEL + x0 + tx;
    tile[i][tx] = flag ? (float)((const bf16*)W)[gi] : ((const float*)W)[gi];
  }
  __syncthreads();
  for (int i = threadIdx.y; i < 32; i += 8)
    T[(size_t)(x0 + i) * D_MODEL + y0 + tx] = (bf16)tile[tx][i];
}

__global__ __launch_bounds__(256) void prep_bias(
    const void* __restrict__ b0, const void* __restrict__ b1,
    const void* __restrict__ b2, const void* __restrict__ b3,
    bf16* __restrict__ o0, bf16* __restrict__ o1,
    bf16* __restrict__ o2, bf16* __restrict__ o3,
    const int* __restrict__ flagp)
{
  const int flag = *flagp;
  const void* B; bf16* O;
  switch (blockIdx.x) {
    case 0:  B = b0; O = o0; break;
    case 1:  B = b1; O = o1; break;
    case 2:  B = b2; O = o2; break;
    default: B = b3; O = o3; break;
  }
  for (int j = 0; j < 4; ++j) {
    const int i = threadIdx.x + j * 256;
    O[i] = flag ? ((const bf16*)B)[i] : (bf16)((const float*)B)[i];
  }
}

// ---------------------------------------------------------------- GEMM A@B^T
// M=4096, N=1024, K=1024. 128x128 tile, 4 waves (2x2 of 64x64), BK=32.
struct GArgs {
  const bf16* A;     // converted A (used when flag==0)
  const void* Araw;  // original input (used as bf16 when flag==1)
  const bf16* BT;    // [1024][1024] bf16, row n = column n of W
  const bf16* bias;  // [1024] bf16
  void* out;
  int mode;          // 0: [m][n] (dtype per flag)  1: [b,h,s,d]  2: [b,h,d,s]
};

__global__ __launch_bounds__(256) void gemm_bt(GArgs g0, GArgs g1, GArgs g2,
                                               const int* __restrict__ flagp)
{
  GArgs g = (blockIdx.z == 0) ? g0 : ((blockIdx.z == 1) ? g1 : g2);
  const int flag = *flagp;
  const bf16* A = flag ? (const bf16*)g.Araw : g.A;

  __shared__ __align__(16) bf16 As[128 * 32];
  __shared__ __align__(16) bf16 Bs[128 * 32];
  const int tid  = threadIdx.x;
  const int wave = tid >> 6, lane = tid & 63;
  const int quad = lane >> 4, l16 = lane & 15;
  const int m0 = blockIdx.y * 128, n0 = blockIdx.x * 128;
  const int wm = (wave >> 1) * 64, wn = (wave & 1) * 64;
  const int srow = lane >> 2;
  const int scol = (lane & 3) * 8;

  f32x4 acc[4][4] = {};

  const bf16* Ag = A    + (size_t)(m0 + wave * 32 + srow) * D_MODEL + scol;
  const bf16* Bg = g.BT + (size_t)(n0 + wave * 32 + srow) * D_MODEL + scol;
  bf16* Asw = As + (wave * 32) * 32;   // wave-uniform LDS base
  bf16* Bsw = Bs + (wave * 32) * 32;

  for (int kt = 0; kt < D_MODEL; kt += 32) {
    __syncthreads();
    gload_lds16(Ag + kt,                Asw);
    gload_lds16(Ag + kt + 16 * D_MODEL, Asw + 16 * 32);
    gload_lds16(Bg + kt,                Bsw);
    gload_lds16(Bg + kt + 16 * D_MODEL, Bsw + 16 * 32);
    __syncthreads();

    bf16x8 af[4], bfv[4];
#pragma unroll
    for (int mi = 0; mi < 4; ++mi)
      af[mi] = *(const bf16x8*)(As + (wm + mi * 16 + l16) * 32 + quad * 8);
#pragma unroll
    for (int ni = 0; ni < 4; ++ni)
      bfv[ni] = *(const bf16x8*)(Bs + (wn + ni * 16 + l16) * 32 + quad * 8);
#pragma unroll
    for (int mi = 0; mi < 4; ++mi)
#pragma unroll
      for (int ni = 0; ni < 4; ++ni)
        acc[mi][ni] = __builtin_amdgcn_mfma_f32_16x16x32_bf16(
            af[mi], bfv[ni], acc[mi][ni], 0, 0, 0);
  }

  // C layout: row = quad*4 + r, col = l16 (m89-verified)
#pragma unroll
  for (int mi = 0; mi < 4; ++mi) {
#pragma unroll
    for (int ni = 0; ni < 4; ++ni) {
      const int col  = n0 + wn + ni * 16 + l16;
      const float bv = (float)g.bias[col];
      const int row0 = m0 + wm + mi * 16 + quad * 4;
      const int b = row0 >> 11, s = row0 & 2047, hh = col >> 6, d = col & 63;
      if (g.mode == 2) {
        bf16x4 pk;
#pragma unroll
        for (int r = 0; r < 4; ++r)
          pk[r] = (bf16)scrub(acc[mi][ni][r] + bv, 300.0f);
        *(bf16x4*)((bf16*)g.out + ((size_t)((b * NH + hh) * DEPTH + d)) * S_LEN + s) = pk;
      } else if (g.mode == 1) {
        bf16* op = (bf16*)g.out + ((size_t)(b * NH + hh) * S_LEN + s) * DEPTH + d;
#pragma unroll
        for (int r = 0; r < 4; ++r)
          op[(size_t)r * DEPTH] = (bf16)scrub(acc[mi][ni][r] + bv, 300.0f);
      } else {
        if (flag) {
          bf16* op = (bf16*)g.out + (size_t)row0 * D_MODEL + col;
#pragma unroll
          for (int r = 0; r < 4; ++r)
            op[(size_t)r * D_MODEL] = (bf16)scrub(acc[mi][ni][r] + bv, 20000.0f);
        } else {
          float* op = (float*)g.out + (size_t)row0 * D_MODEL + col;
#pragma unroll
          for (int r = 0; r < 4; ++r)
            op[(size_t)r * D_MODEL] = scrub(acc[mi][ni][r] + bv, 20000.0f);
        }
      }
    }
  }
}

// ---------------------------------------------------------------- attention
__global__ __launch_bounds__(256) void attn(
    const bf16* __restrict__ Qh, const bf16* __restrict__ Kh,
    const bf16* __restrict__ Vt, const int* __restrict__ mask,
    bf16* __restrict__ Oh)
{
  const int bh = blockIdx.y;
  const int b  = bh >> 4;
  const int h  = bh & 15;
  const int q0 = blockIdx.x * 64;
  const int tid = threadIdx.x, wave = tid >> 6, lane = tid & 63;
  const int quad = lane >> 4, l16 = lane & 15;

  __shared__ __align__(16) bf16 Qs[64][72];
  __shared__ __align__(16) bf16 Ks[64][72];
  __shared__ __align__(16) bf16 Vts[64][72];  // [d][s']
  __shared__ __align__(16) bf16 Ps[4][16][72];
  __shared__ float mf[64];

  const bf16* Qg = Qh + ((size_t)bh * S_LEN + q0) * DEPTH;
  for (int i = tid; i < 512; i += 256) {
    int r = i >> 3, c = (i & 7) * 8;
    *(bf16x8*)(&Qs[r][c]) = *(const bf16x8*)(Qg + r * DEPTH + c);
  }

  float m_run[4], l_run[4];
  f32x4 o_acc[4] = {};
#pragma unroll
  for (int r = 0; r < 4; ++r) { m_run[r] = -1e5f; l_run[r] = 0.f; }

  const float scale2 = 0.125f * LOG2E;
  const bf16* Kg = Kh + (size_t)bh * S_LEN * DEPTH;
  const bf16* Vg = Vt + (size_t)bh * DEPTH * S_LEN;
  const int* mg = mask + b * S_LEN;

  for (int kb = 0; kb < S_LEN; kb += 64) {
    __syncthreads();
    for (int i = tid; i < 512; i += 256) {
      int r = i >> 3, c = (i & 7) * 8;
      *(bf16x8*)(&Ks[r][c])  = *(const bf16x8*)(Kg + (size_t)(kb + r) * DEPTH + c);
      *(bf16x8*)(&Vts[r][c]) = *(const bf16x8*)(Vg + (size_t)r * S_LEN + kb + c);
    }
    if (tid < 64) mf[tid] = MASK_PEN * (float)mg[kb + tid];
    __syncthreads();

    f32x4 sacc[4] = {};
    bf16x8 aq0 = *(const bf16x8*)(&Qs[wave * 16 + l16][quad * 8]);
    bf16x8 aq1 = *(const bf16x8*)(&Qs[wave * 16 + l16][32 + quad * 8]);
#pragma unroll
    for (int jn = 0; jn < 4; ++jn) {
      bf16x8 bk0 = *(const bf16x8*)(&Ks[jn * 16 + l16][quad * 8]);
      bf16x8 bk1 = *(const bf16x8*)(&Ks[jn * 16 + l16][32 + quad * 8]);
      sacc[jn] = __builtin_amdgcn_mfma_f32_16x16x32_bf16(aq0, bk0, sacc[jn], 0, 0, 0);
      sacc[jn] = __builtin_amdgcn_mfma_f32_16x16x32_bf16(aq1, bk1, sacc[jn], 0, 0, 0);
    }

    float sv[4][4];
#pragma unroll
    for (int jn = 0; jn < 4; ++jn) {
      float mcol = mf[jn * 16 + l16];
#pragma unroll
      for (int r = 0; r < 4; ++r)
        sv[jn][r] = sacc[jn][r] * scale2 + mcol;
    }

    float m_new[4], alpha[4];
#pragma unroll
    for (int r = 0; r < 4; ++r) {
      float t = fmaxf(fmaxf(sv[0][r], sv[1][r]), fmaxf(sv[2][r], sv[3][r]));
      t = fmaxf(t, __shfl_xor(t, 1));
      t = fmaxf(t, __shfl_xor(t, 2));
      t = fmaxf(t, __shfl_xor(t, 4));
      t = fmaxf(t, __shfl_xor(t, 8));
      m_new[r] = fmaxf(m_run[r], t);
      alpha[r] = __builtin_amdgcn_exp2f(fmaxf(m_run[r] - m_new[r], -150.f));
      m_run[r] = m_new[r];
    }

#pragma unroll
    for (int r = 0; r < 4; ++r) {
      float rs = 0.f;
#pragma unroll
      for (int jn = 0; jn < 4; ++jn) {
        float p = __builtin_amdgcn_exp2f(fmaxf(sv[jn][r] - m_new[r], -150.f));
        Ps[wave][quad * 4 + r][jn * 16 + l16] = (bf16)p;
        rs += p;
      }
      rs += __shfl_xor(rs, 1);
      rs += __shfl_xor(rs, 2);
      rs += __shfl_xor(rs, 4);
      rs += __shfl_xor(rs, 8);
      l_run[r] = l_run[r] * alpha[r] + rs;
#pragma unroll
      for (int jd = 0; jd < 4; ++jd)
        o_acc[jd][r] *= alpha[r];
    }

    bf16x8 ap0 = *(const bf16x8*)(&Ps[wave][l16][quad * 8]);
    bf16x8 ap1 = *(const bf16x8*)(&Ps[wave][l16][32 + quad * 8]);
#pragma unroll
    for (int jd = 0; jd < 4; ++jd) {
      bf16x8 bv0 = *(const bf16x8*)(&Vts[jd * 16 + l16][quad * 8]);
      bf16x8 bv1 = *(const bf16x8*)(&Vts[jd * 16 + l16][32 + quad * 8]);
      o_acc[jd] = __builtin_amdgcn_mfma_f32_16x16x32_bf16(ap0, bv0, o_acc[jd], 0, 0, 0);
      o_acc[jd] = __builtin_amdgcn_mfma_f32_16x16x32_bf16(ap1, bv1, o_acc[jd], 0, 0, 0);
    }
  }

#pragma unroll
  for (int r = 0; r < 4; ++r) {
    const int s = q0 + wave * 16 + quad * 4 + r;
    const float inv = 1.f / l_run[r];
#pragma unroll
    for (int jd = 0; jd < 4; ++jd) {
      const int d = jd * 16 + l16;
      Oh[(size_t)(b * S_LEN + s) * D_MODEL + h * DEPTH + d] =
          (bf16)scrub(o_acc[jd][r] * inv, 1000.0f);
    }
  }
}

// ---------------------------------------------------------------- launch
extern "C" void kernel_launch(void* const* d_in, const int* in_sizes, int n_in,
                              void* d_out, int out_size, void* d_ws, size_t ws_size,
                              hipStream_t stream)
{
  const void* q    = d_in[0];
  const void* k    = d_in[1];
  const void* v    = d_in[2];
  const int*  mask = (const int*)d_in[3];
  const void* wq   = d_in[4];
  const void* bq   = d_in[5];
  const void* wk   = d_in[6];
  const void* bk   = d_in[7];
  const void* wv   = d_in[8];
  const void* bv   = d_in[9];
  const void* wo   = d_in[10];
  const void* bo   = d_in[11];

  // Workspace layout (bytes). Low region (always used, <=40.1 MB);
  // conversion buffers (only touched when inputs are f32) live at 41-65 MB.
  char* ws = (char*)d_ws;
  const size_t MB = 1u << 20;
  bf16* Qh  = (bf16*)(ws + 0 * MB);    // [b,h,s,d]   8 MB
  bf16* Kh  = (bf16*)(ws + 8 * MB);    // [b,h,s,d]   8 MB
  bf16* Vt  = (bf16*)(ws + 16 * MB);   // [b,h,d,s]   8 MB
  bf16* Oh  = (bf16*)(ws + 24 * MB);   // [b,s,(h d)] 8 MB
  bf16* wqT = (bf16*)(ws + 32 * MB);
  bf16* wkT = (bf16*)(ws + 34 * MB);
  bf16* wvT = (bf16*)(ws + 36 * MB);
  bf16* woT = (bf16*)(ws + 38 * MB);
  bf16* bqb = (bf16*)(ws + 40 * MB);
  bf16* bkb = (bf16*)(ws + 40 * MB + 4096);
  bf16* bvb = (bf16*)(ws + 40 * MB + 8192);
  bf16* bob = (bf16*)(ws + 40 * MB + 12288);
  int*  flag = (int*)(ws + 40 * MB + 32768);
  bf16* qb  = (bf16*)(ws + 41 * MB);   // f32-conversion buffers (flag==0 only)
  bf16* kb_ = (bf16*)(ws + 49 * MB);
  bf16* vb_ = (bf16*)(ws + 57 * MB);

  probe_dtype<<<1, 64, 0, stream>>>((const uint32_t*)q, flag);

  prep_qkv<<<dim3(2048, 1, 3), 256, 0, stream>>>(q, k, v, qb, kb_, vb_, flag);
  prep_w<<<dim3(32, 32, 4), dim3(32, 8), 0, stream>>>(
      wq, wk, wv, wo, wqT, wkT, wvT, woT, flag);
  prep_bias<<<4, 256, 0, stream>>>(bq, bk, bv, bo, bqb, bkb, bvb, bob, flag);

  GArgs gq{qb,  q,  wqT, bqb, Qh, 1};
  GArgs gk{kb_, k,  wkT, bkb, Kh, 1};
  GArgs gv{vb_, v,  wvT, bvb, Vt, 2};
  gemm_bt<<<dim3(8, 32, 3), 256, 0, stream>>>(gq, gk, gv, flag);

  attn<<<dim3(32, 32), 256, 0, stream>>>(Qh, Kh, Vt, mask, Oh);

  GArgs go{Oh, Oh, woT, bob, d_out, 0};
  gemm_bt<<<dim3(8, 32, 1), 256, 0, stream>>>(go, go, go, flag);
}

// Round 4
// 273.925 us; speedup vs baseline: 1.1771x; 1.1771x over previous
//
#include <hip/hip_runtime.h>
#include <hip/hip_bf16.h>
#include <stdint.h>

// MultiHeadAttention: B=2, S=2048, D_MODEL=1024, H=16, depth=64.
// Runtime dtype probe (bf16 vs f32 inputs) + all-bf16 MFMA pipeline.
//
//   0) probe: detect bf16 (flag=1) vs f32 (flag=0) from q's bit patterns
//   1) prep_qkv: if f32, convert q,k,v -> bf16 (skip if bf16)
//   2) prep_w:   transpose weights -> bf16 W^T; wq pre-scaled by 0.125*log2e
//   3) prep_bias: biases -> bf16; bq pre-scaled
//   4) gemm_bt (z=3): projections -> Qh[b,h,s,d], Kh[b,h,s,d], Vt[b,h,d,s]
//   5) attn: flash attention with STATIC-max softmax (exp2 domain).
//      p = exp2(logit2 - 20) is exact up to a global 2^c factor that cancels
//      in o/l. Safe: overflow needs logit2>147 (logits ~N(0,1)); harmful
//      underflow needs logit2<-106 (only masked entries, which must be 0).
//      Row sums l via an extra MFMA with all-ones B (accumulates like O).
//   6) gemm_bt (mode 0): Oh @ wo^T + bo -> out (bf16 or f32 per flag)

typedef __bf16 bf16;
typedef __bf16 bf16x8 __attribute__((ext_vector_type(8)));
typedef __bf16 bf16x4 __attribute__((ext_vector_type(4)));
typedef float  f32x4  __attribute__((ext_vector_type(4)));

#define D_MODEL 1024
#define S_LEN   2048
#define NH      16
#define DEPTH   64

#define LOG2E   1.4426950408889634f
#define QSCALE  (0.125f * LOG2E)     // folded into wq/bq at prep time
#define SMAX    20.0f                // static softmax max (log2 domain)
#define MPEN    (-30000.0f)          // masked: exp2(~-30000) == +0 exactly

__device__ __forceinline__ void gload_lds16(const void* g, void* l) {
  __builtin_amdgcn_global_load_lds(
      (__attribute__((address_space(1))) void*)g,
      (__attribute__((address_space(3))) void*)l,
      16, 0, 0);
}

// ---------------------------------------------------------------- dtype probe
__global__ void probe_dtype(const uint32_t* __restrict__ qw, int* __restrict__ flag)
{
  const int t = threadIdx.x;  // 64 threads
  int c = 0;
  for (int i = 0; i < 4; ++i) {
    uint32_t w = qw[t * 4 + i];
    uint32_t e = (w >> 7) & 0xFF;
    c += (e >= 90 && e <= 150) ? 1 : 0;
  }
  for (int s = 1; s < 64; s <<= 1) c += __shfl_xor(c, s);
  if (t == 0) *flag = (c > 160) ? 1 : 0;
}

// ---------------------------------------------------------------- conversion
__global__ __launch_bounds__(256) void prep_qkv(
    const void* __restrict__ q, const void* __restrict__ k,
    const void* __restrict__ v,
    bf16* __restrict__ qb, bf16* __restrict__ kb, bf16* __restrict__ vb,
    const int* __restrict__ flagp)
{
  if (*flagp) return;  // already bf16: gemm reads the raw pointers
  const void* src; bf16* dst;
  switch (blockIdx.z) {
    case 0:  src = q; dst = qb; break;
    case 1:  src = k; dst = kb; break;
    default: src = v; dst = vb; break;
  }
  const size_t idx = ((size_t)blockIdx.x * 256 + threadIdx.x) * 8;
  const float* s = (const float*)src + idx;
  f32x4 a = *(const f32x4*)(s);
  f32x4 b = *(const f32x4*)(s + 4);
  bf16x8 o;
  for (int i = 0; i < 4; ++i) { o[i] = (bf16)a[i]; o[4 + i] = (bf16)b[i]; }
  *(bf16x8*)(dst + idx) = o;
}

__global__ __launch_bounds__(256) void prep_w(
    const void* __restrict__ w0, const void* __restrict__ w1,
    const void* __restrict__ w2, const void* __restrict__ w3,
    bf16* __restrict__ t0, bf16* __restrict__ t1,
    bf16* __restrict__ t2, bf16* __restrict__ t3,
    const int* __restrict__ flagp)
{
  const int flag = *flagp;
  const void* W; bf16* T;
  switch (blockIdx.z) {
    case 0:  W = w0; T = t0; break;
    case 1:  W = w1; T = t1; break;
    case 2:  W = w2; T = t2; break;
    default: W = w3; T = t3; break;
  }
  const float sc = (blockIdx.z == 0) ? QSCALE : 1.0f;
  __shared__ float tile[32][33];
  const int tx = threadIdx.x;            // 0..31
  const int x0 = blockIdx.x * 32;        // col
  const int y0 = blockIdx.y * 32;        // row
  for (int i = threadIdx.y; i < 32; i += 8) {
    const size_t gi = (size_t)(y0 + i) * D_MODEL + x0 + tx;
    tile[i][tx] = flag ? (float)((const bf16*)W)[gi] : ((const float*)W)[gi];
  }
  __syncthreads();
  for (int i = threadIdx.y; i < 32; i += 8)
    T[(size_t)(x0 + i) * D_MODEL + y0 + tx] = (bf16)(tile[tx][i] * sc);
}

__global__ __launch_bounds__(256) void prep_bias(
    const void* __restrict__ b0, const void* __restrict__ b1,
    const void* __restrict__ b2, const void* __restrict__ b3,
    bf16* __restrict__ o0, bf16* __restrict__ o1,
    bf16* __restrict__ o2, bf16* __restrict__ o3,
    const int* __restrict__ flagp)
{
  const int flag = *flagp;
  const void* B; bf16* O;
  switch (blockIdx.x) {
    case 0:  B = b0; O = o0; break;
    case 1:  B = b1; O = o1; break;
    case 2:  B = b2; O = o2; break;
    default: B = b3; O = o3; break;
  }
  const float sc = (blockIdx.x == 0) ? QSCALE : 1.0f;
  for (int j = 0; j < 4; ++j) {
    const int i = threadIdx.x + j * 256;
    const float v = flag ? (float)((const bf16*)B)[i] : ((const float*)B)[i];
    O[i] = (bf16)(v * sc);
  }
}

// ---------------------------------------------------------------- GEMM A@B^T
// M=4096, N=1024, K=1024. 128x128 tile, 4 waves (2x2 of 64x64), BK=32.
struct GArgs {
  const bf16* A;     // converted A (used when flag==0)
  const void* Araw;  // original input (used as bf16 when flag==1)
  const bf16* BT;    // [1024][1024] bf16, row n = column n of W
  const bf16* bias;  // [1024] bf16
  void* out;
  int mode;          // 0: [m][n] (dtype per flag)  1: [b,h,s,d]  2: [b,h,d,s]
};

__global__ __launch_bounds__(256) void gemm_bt(GArgs g0, GArgs g1, GArgs g2,
                                               const int* __restrict__ flagp)
{
  GArgs g = (blockIdx.z == 0) ? g0 : ((blockIdx.z == 1) ? g1 : g2);
  const int flag = *flagp;
  const bf16* A = flag ? (const bf16*)g.Araw : g.A;

  __shared__ __align__(16) bf16 As[128 * 32];
  __shared__ __align__(16) bf16 Bs[128 * 32];
  const int tid  = threadIdx.x;
  const int wave = tid >> 6, lane = tid & 63;
  const int quad = lane >> 4, l16 = lane & 15;
  const int m0 = blockIdx.y * 128, n0 = blockIdx.x * 128;
  const int wm = (wave >> 1) * 64, wn = (wave & 1) * 64;
  const int srow = lane >> 2;
  const int scol = (lane & 3) * 8;

  f32x4 acc[4][4] = {};

  const bf16* Ag = A    + (size_t)(m0 + wave * 32 + srow) * D_MODEL + scol;
  const bf16* Bg = g.BT + (size_t)(n0 + wave * 32 + srow) * D_MODEL + scol;
  bf16* Asw = As + (wave * 32) * 32;   // wave-uniform LDS base
  bf16* Bsw = Bs + (wave * 32) * 32;

  for (int kt = 0; kt < D_MODEL; kt += 32) {
    __syncthreads();
    gload_lds16(Ag + kt,                Asw);
    gload_lds16(Ag + kt + 16 * D_MODEL, Asw + 16 * 32);
    gload_lds16(Bg + kt,                Bsw);
    gload_lds16(Bg + kt + 16 * D_MODEL, Bsw + 16 * 32);
    __syncthreads();

    bf16x8 af[4], bfv[4];
#pragma unroll
    for (int mi = 0; mi < 4; ++mi)
      af[mi] = *(const bf16x8*)(As + (wm + mi * 16 + l16) * 32 + quad * 8);
#pragma unroll
    for (int ni = 0; ni < 4; ++ni)
      bfv[ni] = *(const bf16x8*)(Bs + (wn + ni * 16 + l16) * 32 + quad * 8);
#pragma unroll
    for (int mi = 0; mi < 4; ++mi)
#pragma unroll
      for (int ni = 0; ni < 4; ++ni)
        acc[mi][ni] = __builtin_amdgcn_mfma_f32_16x16x32_bf16(
            af[mi], bfv[ni], acc[mi][ni], 0, 0, 0);
  }

  // C layout: row = quad*4 + r, col = l16 (m89-verified)
#pragma unroll
  for (int mi = 0; mi < 4; ++mi) {
#pragma unroll
    for (int ni = 0; ni < 4; ++ni) {
      const int col  = n0 + wn + ni * 16 + l16;
      const float bv = (float)g.bias[col];
      const int row0 = m0 + wm + mi * 16 + quad * 4;
      const int b = row0 >> 11, s = row0 & 2047, hh = col >> 6, d = col & 63;
      if (g.mode == 2) {
        bf16x4 pk;
#pragma unroll
        for (int r = 0; r < 4; ++r)
          pk[r] = (bf16)(acc[mi][ni][r] + bv);
        *(bf16x4*)((bf16*)g.out + ((size_t)((b * NH + hh) * DEPTH + d)) * S_LEN + s) = pk;
      } else if (g.mode == 1) {
        bf16* op = (bf16*)g.out + ((size_t)(b * NH + hh) * S_LEN + s) * DEPTH + d;
#pragma unroll
        for (int r = 0; r < 4; ++r)
          op[(size_t)r * DEPTH] = (bf16)(acc[mi][ni][r] + bv);
      } else {
        if (flag) {
          bf16* op = (bf16*)g.out + (size_t)row0 * D_MODEL + col;
#pragma unroll
          for (int r = 0; r < 4; ++r)
            op[(size_t)r * D_MODEL] = (bf16)(acc[mi][ni][r] + bv);
        } else {
          float* op = (float*)g.out + (size_t)row0 * D_MODEL + col;
#pragma unroll
          for (int r = 0; r < 4; ++r)
            op[(size_t)r * D_MODEL] = acc[mi][ni][r] + bv;
        }
      }
    }
  }
}

// ---------------------------------------------------------------- attention
// grid (32 q-tiles, 32 bh), 256 thr = 4 waves; wave w owns q-rows
// [q0+w*16, +16). 64-key blocks. Static-max softmax: no running max, no
// rescale, no shuffles. Row sums via ones-MFMA.
__global__ __launch_bounds__(256) void attn(
    const bf16* __restrict__ Qh, const bf16* __restrict__ Kh,
    const bf16* __restrict__ Vt, const int* __restrict__ mask,
    bf16* __restrict__ Oh)
{
  const int bh = blockIdx.y;
  const int b  = bh >> 4;
  const int h  = bh & 15;
  const int q0 = blockIdx.x * 64;
  const int tid = threadIdx.x, wave = tid >> 6, lane = tid & 63;
  const int quad = lane >> 4, l16 = lane & 15;

  __shared__ __align__(16) bf16 Ks[64][72];
  __shared__ __align__(16) bf16 Vts[64][72];   // [d][s']
  __shared__ __align__(16) bf16 Ps[4][16][72]; // per-wave P tile (same-wave RW)
  __shared__ float mf2[S_LEN];                 // additive mask+(-SMAX), log2 dom

  // mask row for this batch (written once; first loop-top barrier orders it)
  const int* mg = mask + b * S_LEN;
  for (int i = tid; i < S_LEN; i += 256)
    mf2[i] = mg[i] ? (MPEN - SMAX) : (-SMAX);

  // Q fragments straight from global (Q is pre-scaled by QSCALE)
  const bf16* Qg = Qh + ((size_t)bh * S_LEN + q0 + wave * 16 + l16) * DEPTH;
  bf16x8 aq0 = *(const bf16x8*)(Qg + quad * 8);
  bf16x8 aq1 = *(const bf16x8*)(Qg + 32 + quad * 8);

  bf16x8 ones;
#pragma unroll
  for (int j = 0; j < 8; ++j) ones[j] = (bf16)1.0f;

  f32x4 o_acc[4] = {};
  f32x4 l_acc = {};

  const bf16* Kg = Kh + (size_t)bh * S_LEN * DEPTH;
  const bf16* Vg = Vt + (size_t)bh * DEPTH * S_LEN;

  for (int kb = 0; kb < S_LEN; kb += 64) {
    __syncthreads();
    for (int i = tid; i < 512; i += 256) {
      int r = i >> 3, c = (i & 7) * 8;
      *(bf16x8*)(&Ks[r][c])  = *(const bf16x8*)(Kg + (size_t)(kb + r) * DEPTH + c);
      *(bf16x8*)(&Vts[r][c]) = *(const bf16x8*)(Vg + (size_t)r * S_LEN + kb + c);
    }
    __syncthreads();

    // S = Q K^T : 16 q-rows x 64 keys (log2 domain already)
    f32x4 sacc[4] = {};
#pragma unroll
    for (int jn = 0; jn < 4; ++jn) {
      bf16x8 bk0 = *(const bf16x8*)(&Ks[jn * 16 + l16][quad * 8]);
      bf16x8 bk1 = *(const bf16x8*)(&Ks[jn * 16 + l16][32 + quad * 8]);
      sacc[jn] = __builtin_amdgcn_mfma_f32_16x16x32_bf16(aq0, bk0, sacc[jn], 0, 0, 0);
      sacc[jn] = __builtin_amdgcn_mfma_f32_16x16x32_bf16(aq1, bk1, sacc[jn], 0, 0, 0);
    }

    // p = exp2(s + mask - SMAX); store to Ps (C row = quad*4+r, col = jn*16+l16)
#pragma unroll
    for (int jn = 0; jn < 4; ++jn) {
      const float mc = mf2[kb + jn * 16 + l16];
#pragma unroll
      for (int r = 0; r < 4; ++r)
        Ps[wave][quad * 4 + r][jn * 16 + l16] =
            (bf16)__builtin_amdgcn_exp2f(sacc[jn][r] + mc);
    }

    // O += P @ V ; l += P @ 1  (Ps same-wave write->read: DS in-order)
    bf16x8 ap0 = *(const bf16x8*)(&Ps[wave][l16][quad * 8]);
    bf16x8 ap1 = *(const bf16x8*)(&Ps[wave][l16][32 + quad * 8]);
#pragma unroll
    for (int jd = 0; jd < 4; ++jd) {
      bf16x8 bv0 = *(const bf16x8*)(&Vts[jd * 16 + l16][quad * 8]);
      bf16x8 bv1 = *(const bf16x8*)(&Vts[jd * 16 + l16][32 + quad * 8]);
      o_acc[jd] = __builtin_amdgcn_mfma_f32_16x16x32_bf16(ap0, bv0, o_acc[jd], 0, 0, 0);
      o_acc[jd] = __builtin_amdgcn_mfma_f32_16x16x32_bf16(ap1, bv1, o_acc[jd], 0, 0, 0);
    }
    l_acc = __builtin_amdgcn_mfma_f32_16x16x32_bf16(ap0, ones, l_acc, 0, 0, 0);
    l_acc = __builtin_amdgcn_mfma_f32_16x16x32_bf16(ap1, ones, l_acc, 0, 0, 0);
  }

#pragma unroll
  for (int r = 0; r < 4; ++r) {
    const int s = q0 + wave * 16 + quad * 4 + r;
    const float inv = 1.f / l_acc[r];
#pragma unroll
    for (int jd = 0; jd < 4; ++jd) {
      const int d = jd * 16 + l16;
      Oh[(size_t)(b * S_LEN + s) * D_MODEL + h * DEPTH + d] =
          (bf16)(o_acc[jd][r] * inv);
    }
  }
}

// ---------------------------------------------------------------- launch
extern "C" void kernel_launch(void* const* d_in, const int* in_sizes, int n_in,
                              void* d_out, int out_size, void* d_ws, size_t ws_size,
                              hipStream_t stream)
{
  const void* q    = d_in[0];
  const void* k    = d_in[1];
  const void* v    = d_in[2];
  const int*  mask = (const int*)d_in[3];
  const void* wq   = d_in[4];
  const void* bq   = d_in[5];
  const void* wk   = d_in[6];
  const void* bk   = d_in[7];
  const void* wv   = d_in[8];
  const void* bv   = d_in[9];
  const void* wo   = d_in[10];
  const void* bo   = d_in[11];

  char* ws = (char*)d_ws;
  const size_t MB = 1u << 20;
  bf16* Qh  = (bf16*)(ws + 0 * MB);    // [b,h,s,d]   8 MB (pre-scaled)
  bf16* Kh  = (bf16*)(ws + 8 * MB);    // [b,h,s,d]   8 MB
  bf16* Vt  = (bf16*)(ws + 16 * MB);   // [b,h,d,s]   8 MB
  bf16* Oh  = (bf16*)(ws + 24 * MB);   // [b,s,(h d)] 8 MB
  bf16* wqT = (bf16*)(ws + 32 * MB);
  bf16* wkT = (bf16*)(ws + 34 * MB);
  bf16* wvT = (bf16*)(ws + 36 * MB);
  bf16* woT = (bf16*)(ws + 38 * MB);
  bf16* bqb = (bf16*)(ws + 40 * MB);
  bf16* bkb = (bf16*)(ws + 40 * MB + 4096);
  bf16* bvb = (bf16*)(ws + 40 * MB + 8192);
  bf16* bob = (bf16*)(ws + 40 * MB + 12288);
  int*  flag = (int*)(ws + 40 * MB + 32768);
  bf16* qb  = (bf16*)(ws + 41 * MB);   // f32-conversion buffers (flag==0 only)
  bf16* kb_ = (bf16*)(ws + 49 * MB);
  bf16* vb_ = (bf16*)(ws + 57 * MB);

  probe_dtype<<<1, 64, 0, stream>>>((const uint32_t*)q, flag);

  prep_qkv<<<dim3(2048, 1, 3), 256, 0, stream>>>(q, k, v, qb, kb_, vb_, flag);
  prep_w<<<dim3(32, 32, 4), dim3(32, 8), 0, stream>>>(
      wq, wk, wv, wo, wqT, wkT, wvT, woT, flag);
  prep_bias<<<4, 256, 0, stream>>>(bq, bk, bv, bo, bqb, bkb, bvb, bob, flag);

  GArgs gq{qb,  q,  wqT, bqb, Qh, 1};
  GArgs gk{kb_, k,  wkT, bkb, Kh, 1};
  GArgs gv{vb_, v,  wvT, bvb, Vt, 2};
  gemm_bt<<<dim3(8, 32, 3), 256, 0, stream>>>(gq, gk, gv, flag);

  attn<<<dim3(32, 32), 256, 0, stream>>>(Qh, Kh, Vt, mask, Oh);

  GArgs go{Oh, Oh, woT, bob, d_out, 0};
  gemm_bt<<<dim3(8, 32, 1), 256, 0, stream>>>(go, go, go, flag);
}

// Round 5
// 240.909 us; speedup vs baseline: 1.3384x; 1.1370x over previous
//
#include <hip/hip_runtime.h>
#include <hip/hip_bf16.h>
#include <stdint.h>

// MultiHeadAttention: B=2, S=2048, D_MODEL=1024, H=16, depth=64.
// Runtime dtype probe (bf16 vs f32 inputs) + all-bf16 MFMA pipeline.
//
//   0) probe: detect bf16 (flag=1) vs f32 (flag=0) from q's bit patterns
//   0b) scan_mask: per-batch exclusive scan of unmasked keys -> cpos[b][s]
//       (-1 if masked), nb[b]. Masked keys contribute exp(x-1e9)=+0 EXACTLY
//       in fp32, so key compaction is exact (~2x less attention work).
//   1) prep_qkv: if f32, convert q,k,v -> bf16 (skip if bf16)
//   2) prep_w:   transpose weights -> bf16 W^T; wq pre-scaled by 0.125*log2e
//   3) prep_bias: biases -> bf16; bq pre-scaled
//   4) gemm_bt (z=3): projections -> Qh[b,h,s,d] (all queries),
//      Kc[b,h,j,d], Vc[b,h,d,j] compacted to unmasked keys j=cpos[s]
//   5) attn: flash attention over compact keys, STATIC-max softmax
//      (exp2 domain; p=exp2(logit2-20), global 2^c factor cancels in o/l).
//      128 q-rows/block, 32 q-rows/WAVE: each K/V LDS fragment read feeds
//      2 MFMAs (halves LDS-read traffic/work — LDS pipe was the R4 bottleneck).
//      Row sums l via ones-MFMA. Pad-tail keys killed by -30000 penalty.
//   6) gemm_bt (mode 0): Oh @ wo^T + bo -> out (bf16 or f32 per flag)

typedef __bf16 bf16;
typedef __bf16 bf16x8 __attribute__((ext_vector_type(8)));
typedef __bf16 bf16x4 __attribute__((ext_vector_type(4)));
typedef float  f32x4  __attribute__((ext_vector_type(4)));

#define D_MODEL 1024
#define S_LEN   2048
#define NH      16
#define DEPTH   64

#define LOG2E   1.4426950408889634f
#define QSCALE  (0.125f * LOG2E)     // folded into wq/bq at prep time
#define SMAX    20.0f                // static softmax max (log2 domain)
#define PADPEN  (-30000.0f)          // pad keys: exp2(~-30000) == +0 exactly

__device__ __forceinline__ void gload_lds16(const void* g, void* l) {
  __builtin_amdgcn_global_load_lds(
      (__attribute__((address_space(1))) void*)g,
      (__attribute__((address_space(3))) void*)l,
      16, 0, 0);
}

// ---------------------------------------------------------------- dtype probe
__global__ void probe_dtype(const uint32_t* __restrict__ qw, int* __restrict__ flag)
{
  const int t = threadIdx.x;  // 64 threads
  int c = 0;
  for (int i = 0; i < 4; ++i) {
    uint32_t w = qw[t * 4 + i];
    uint32_t e = (w >> 7) & 0xFF;
    c += (e >= 90 && e <= 150) ? 1 : 0;
  }
  for (int s = 1; s < 64; s <<= 1) c += __shfl_xor(c, s);
  if (t == 0) *flag = (c > 160) ? 1 : 0;
}

// ---------------------------------------------------------------- mask scan
// grid(2) blocks (one per batch), 256 threads. cpos[s] = compact index of
// key s if unmasked else -1; nb[b] = number of unmasked keys.
__global__ __launch_bounds__(256) void scan_mask(
    const int* __restrict__ mask, int* __restrict__ cpos, int* __restrict__ nb)
{
  const int b = blockIdx.x;
  const int t = threadIdx.x;
  const int lane = t & 63, wv = t >> 6;
  __shared__ int wsum[4];

  int vals[8], s = 0;
#pragma unroll
  for (int j = 0; j < 8; ++j) {
    vals[j] = (mask[b * S_LEN + t * 8 + j] == 0) ? 1 : 0;
    s += vals[j];
  }
  int acc = s;  // wave-inclusive scan
  for (int off = 1; off < 64; off <<= 1) {
    int u = __shfl_up(acc, off);
    if (lane >= off) acc += u;
  }
  if (lane == 63) wsum[wv] = acc;
  __syncthreads();
  int base = 0;
  for (int w = 0; w < 4; ++w) base += (w < wv) ? wsum[w] : 0;
  int ex = base + acc - s;  // exclusive prefix for this thread's first elem
#pragma unroll
  for (int j = 0; j < 8; ++j) {
    cpos[b * S_LEN + t * 8 + j] = vals[j] ? ex : -1;
    ex += vals[j];
  }
  if (t == 255) nb[b] = base + acc;
}

// ---------------------------------------------------------------- conversion
__global__ __launch_bounds__(256) void prep_qkv(
    const void* __restrict__ q, const void* __restrict__ k,
    const void* __restrict__ v,
    bf16* __restrict__ qb, bf16* __restrict__ kb, bf16* __restrict__ vb,
    const int* __restrict__ flagp)
{
  if (*flagp) return;  // already bf16: gemm reads the raw pointers
  const void* src; bf16* dst;
  switch (blockIdx.z) {
    case 0:  src = q; dst = qb; break;
    case 1:  src = k; dst = kb; break;
    default: src = v; dst = vb; break;
  }
  const size_t idx = ((size_t)blockIdx.x * 256 + threadIdx.x) * 8;
  const float* s = (const float*)src + idx;
  f32x4 a = *(const f32x4*)(s);
  f32x4 b = *(const f32x4*)(s + 4);
  bf16x8 o;
  for (int i = 0; i < 4; ++i) { o[i] = (bf16)a[i]; o[4 + i] = (bf16)b[i]; }
  *(bf16x8*)(dst + idx) = o;
}

__global__ __launch_bounds__(256) void prep_w(
    const void* __restrict__ w0, const void* __restrict__ w1,
    const void* __restrict__ w2, const void* __restrict__ w3,
    bf16* __restrict__ t0, bf16* __restrict__ t1,
    bf16* __restrict__ t2, bf16* __restrict__ t3,
    const int* __restrict__ flagp)
{
  const int flag = *flagp;
  const void* W; bf16* T;
  switch (blockIdx.z) {
    case 0:  W = w0; T = t0; break;
    case 1:  W = w1; T = t1; break;
    case 2:  W = w2; T = t2; break;
    default: W = w3; T = t3; break;
  }
  const float sc = (blockIdx.z == 0) ? QSCALE : 1.0f;
  __shared__ float tile[32][33];
  const int tx = threadIdx.x;            // 0..31
  const int x0 = blockIdx.x * 32;        // col
  const int y0 = blockIdx.y * 32;        // row
  for (int i = threadIdx.y; i < 32; i += 8) {
    const size_t gi = (size_t)(y0 + i) * D_MODEL + x0 + tx;
    tile[i][tx] = flag ? (float)((const bf16*)W)[gi] : ((const float*)W)[gi];
  }
  __syncthreads();
  for (int i = threadIdx.y; i < 32; i += 8)
    T[(size_t)(x0 + i) * D_MODEL + y0 + tx] = (bf16)(tile[tx][i] * sc);
}

__global__ __launch_bounds__(256) void prep_bias(
    const void* __restrict__ b0, const void* __restrict__ b1,
    const void* __restrict__ b2, const void* __restrict__ b3,
    bf16* __restrict__ o0, bf16* __restrict__ o1,
    bf16* __restrict__ o2, bf16* __restrict__ o3,
    const int* __restrict__ flagp)
{
  const int flag = *flagp;
  const void* B; bf16* O;
  switch (blockIdx.x) {
    case 0:  B = b0; O = o0; break;
    case 1:  B = b1; O = o1; break;
    case 2:  B = b2; O = o2; break;
    default: B = b3; O = o3; break;
  }
  const float sc = (blockIdx.x == 0) ? QSCALE : 1.0f;
  for (int j = 0; j < 4; ++j) {
    const int i = threadIdx.x + j * 256;
    const float v = flag ? (float)((const bf16*)B)[i] : ((const float*)B)[i];
    O[i] = (bf16)(v * sc);
  }
}

// ---------------------------------------------------------------- GEMM A@B^T
// M=4096, N=1024, K=1024. 128x128 tile, 4 waves (2x2 of 64x64), BK=32.
struct GArgs {
  const bf16* A;     // converted A (used when flag==0)
  const void* Araw;  // original input (used as bf16 when flag==1)
  const bf16* BT;    // [1024][1024] bf16, row n = column n of W
  const bf16* bias;  // [1024] bf16
  void* out;
  const int* cpos;   // compact index per (b,s), modes 2/3 only
  int mode;          // 0: [m][n] per flag  1: Qh[b,h,s,d]
                     // 2: Vc[b,h,d,j] compact  3: Kc[b,h,j,d] compact
};

__global__ __launch_bounds__(256) void gemm_bt(GArgs g0, GArgs g1, GArgs g2,
                                               const int* __restrict__ flagp)
{
  GArgs g = (blockIdx.z == 0) ? g0 : ((blockIdx.z == 1) ? g1 : g2);
  const int flag = *flagp;
  const bf16* A = flag ? (const bf16*)g.Araw : g.A;

  __shared__ __align__(16) bf16 As[128 * 32];
  __shared__ __align__(16) bf16 Bs[128 * 32];
  const int tid  = threadIdx.x;
  const int wave = tid >> 6, lane = tid & 63;
  const int quad = lane >> 4, l16 = lane & 15;
  const int m0 = blockIdx.y * 128, n0 = blockIdx.x * 128;
  const int wm = (wave >> 1) * 64, wn = (wave & 1) * 64;
  const int srow = lane >> 2;
  const int scol = (lane & 3) * 8;

  f32x4 acc[4][4] = {};

  const bf16* Ag = A    + (size_t)(m0 + wave * 32 + srow) * D_MODEL + scol;
  const bf16* Bg = g.BT + (size_t)(n0 + wave * 32 + srow) * D_MODEL + scol;
  bf16* Asw = As + (wave * 32) * 32;   // wave-uniform LDS base
  bf16* Bsw = Bs + (wave * 32) * 32;

  for (int kt = 0; kt < D_MODEL; kt += 32) {
    __syncthreads();
    gload_lds16(Ag + kt,                Asw);
    gload_lds16(Ag + kt + 16 * D_MODEL, Asw + 16 * 32);
    gload_lds16(Bg + kt,                Bsw);
    gload_lds16(Bg + kt + 16 * D_MODEL, Bsw + 16 * 32);
    __syncthreads();

    bf16x8 af[4], bfv[4];
#pragma unroll
    for (int mi = 0; mi < 4; ++mi)
      af[mi] = *(const bf16x8*)(As + (wm + mi * 16 + l16) * 32 + quad * 8);
#pragma unroll
    for (int ni = 0; ni < 4; ++ni)
      bfv[ni] = *(const bf16x8*)(Bs + (wn + ni * 16 + l16) * 32 + quad * 8);
#pragma unroll
    for (int mi = 0; mi < 4; ++mi)
#pragma unroll
      for (int ni = 0; ni < 4; ++ni)
        acc[mi][ni] = __builtin_amdgcn_mfma_f32_16x16x32_bf16(
            af[mi], bfv[ni], acc[mi][ni], 0, 0, 0);
  }

  // C layout: row = quad*4 + r, col = l16 (m89-verified)
#pragma unroll
  for (int mi = 0; mi < 4; ++mi) {
    const int row0 = m0 + wm + mi * 16 + quad * 4;
    const int b = row0 >> 11, s = row0 & 2047;
    int cp[4];
    if (g.mode >= 2) {
#pragma unroll
      for (int r = 0; r < 4; ++r) cp[r] = g.cpos[b * S_LEN + s + r];
    }
#pragma unroll
    for (int ni = 0; ni < 4; ++ni) {
      const int col  = n0 + wn + ni * 16 + l16;
      const float bv = (float)g.bias[col];
      const int hh = col >> 6, d = col & 63;
      if (g.mode == 3) {          // Kc[b,h,j,d]
        bf16* base = (bf16*)g.out + (size_t)(b * NH + hh) * S_LEN * DEPTH + d;
#pragma unroll
        for (int r = 0; r < 4; ++r)
          if (cp[r] >= 0) base[(size_t)cp[r] * DEPTH] = (bf16)(acc[mi][ni][r] + bv);
      } else if (g.mode == 2) {   // Vc[b,h,d,j]
        bf16* base = (bf16*)g.out + ((size_t)(b * NH + hh) * DEPTH + d) * S_LEN;
#pragma unroll
        for (int r = 0; r < 4; ++r)
          if (cp[r] >= 0) base[cp[r]] = (bf16)(acc[mi][ni][r] + bv);
      } else if (g.mode == 1) {   // Qh[b,h,s,d]
        bf16* op = (bf16*)g.out + ((size_t)(b * NH + hh) * S_LEN + s) * DEPTH + d;
#pragma unroll
        for (int r = 0; r < 4; ++r)
          op[(size_t)r * DEPTH] = (bf16)(acc[mi][ni][r] + bv);
      } else {
        if (flag) {
          bf16* op = (bf16*)g.out + (size_t)row0 * D_MODEL + col;
#pragma unroll
          for (int r = 0; r < 4; ++r)
            op[(size_t)r * D_MODEL] = (bf16)(acc[mi][ni][r] + bv);
        } else {
          float* op = (float*)g.out + (size_t)row0 * D_MODEL + col;
#pragma unroll
          for (int r = 0; r < 4; ++r)
            op[(size_t)r * D_MODEL] = acc[mi][ni][r] + bv;
        }
      }
    }
  }
}

// ---------------------------------------------------------------- attention
// grid (16 q-tiles, 32 bh), 256 thr = 4 waves; wave w owns q-rows
// [q0+w*32, +32) as two 16-row sub-tiles. Keys: compacted, 64-key blocks up
// to nb_pad. Static-max softmax; pad keys killed by -30000 penalty.
__global__ __launch_bounds__(256) void attn(
    const bf16* __restrict__ Qh, const bf16* __restrict__ Kc,
    const bf16* __restrict__ Vc, const int* __restrict__ nbp,
    bf16* __restrict__ Oh)
{
  const int bh = blockIdx.y;
  const int b  = bh >> 4;
  const int h  = bh & 15;
  const int q0 = blockIdx.x * 128;
  const int tid = threadIdx.x, wave = tid >> 6, lane = tid & 63;
  const int quad = lane >> 4, l16 = lane & 15;

  __shared__ __align__(16) bf16 Ks[64][72];
  __shared__ __align__(16) bf16 Vts[64][72];    // [d][j']
  __shared__ __align__(16) bf16 Ps[4][32][72];  // per-wave P tile

  const int nbv = nbp[b];
  const int nb_pad = (nbv + 63) & ~63;

  // Q fragments straight from global (Q is pre-scaled by QSCALE)
  const bf16* Qg = Qh + ((size_t)bh * S_LEN + q0 + wave * 32) * DEPTH;
  bf16x8 aq00 = *(const bf16x8*)(Qg + (size_t)l16 * DEPTH + quad * 8);
  bf16x8 aq01 = *(const bf16x8*)(Qg + (size_t)l16 * DEPTH + 32 + quad * 8);
  bf16x8 aq10 = *(const bf16x8*)(Qg + (size_t)(16 + l16) * DEPTH + quad * 8);
  bf16x8 aq11 = *(const bf16x8*)(Qg + (size_t)(16 + l16) * DEPTH + 32 + quad * 8);

  bf16x8 ones;
#pragma unroll
  for (int j = 0; j < 8; ++j) ones[j] = (bf16)1.0f;

  f32x4 o_acc[2][4] = {};
  f32x4 l_acc[2] = {};

  const bf16* Kg = Kc + (size_t)bh * S_LEN * DEPTH;
  const bf16* Vg = Vc + (size_t)bh * DEPTH * S_LEN;

  for (int kb = 0; kb < nb_pad; kb += 64) {
    __syncthreads();
    for (int i = tid; i < 512; i += 256) {
      int r = i >> 3, c = (i & 7) * 8;
      *(bf16x8*)(&Ks[r][c])  = *(const bf16x8*)(Kg + (size_t)(kb + r) * DEPTH + c);
      *(bf16x8*)(&Vts[r][c]) = *(const bf16x8*)(Vg + (size_t)r * S_LEN + kb + c);
    }
    __syncthreads();

    // S = Q K^T : 32 q-rows x 64 keys; each bk pair feeds both q sub-tiles
    f32x4 sacc[2][4] = {};
#pragma unroll
    for (int jn = 0; jn < 4; ++jn) {
      bf16x8 bk0 = *(const bf16x8*)(&Ks[jn * 16 + l16][quad * 8]);
      bf16x8 bk1 = *(const bf16x8*)(&Ks[jn * 16 + l16][32 + quad * 8]);
      sacc[0][jn] = __builtin_amdgcn_mfma_f32_16x16x32_bf16(aq00, bk0, sacc[0][jn], 0, 0, 0);
      sacc[0][jn] = __builtin_amdgcn_mfma_f32_16x16x32_bf16(aq01, bk1, sacc[0][jn], 0, 0, 0);
      sacc[1][jn] = __builtin_amdgcn_mfma_f32_16x16x32_bf16(aq10, bk0, sacc[1][jn], 0, 0, 0);
      sacc[1][jn] = __builtin_amdgcn_mfma_f32_16x16x32_bf16(aq11, bk1, sacc[1][jn], 0, 0, 0);
    }

    // p = exp2(s - SMAX), pad keys -> exactly 0
#pragma unroll
    for (int jn = 0; jn < 4; ++jn) {
      const int key = kb + jn * 16 + l16;
      const float pen = (key < nbv) ? (-SMAX) : PADPEN;
#pragma unroll
      for (int qs = 0; qs < 2; ++qs)
#pragma unroll
        for (int r = 0; r < 4; ++r)
          Ps[wave][qs * 16 + quad * 4 + r][jn * 16 + l16] =
              (bf16)__builtin_amdgcn_exp2f(sacc[qs][jn][r] + pen);
    }

    // O += P @ V ; l += P @ 1  (Ps same-wave write->read: DS in-order)
    bf16x8 ap00 = *(const bf16x8*)(&Ps[wave][l16][quad * 8]);
    bf16x8 ap01 = *(const bf16x8*)(&Ps[wave][l16][32 + quad * 8]);
    bf16x8 ap10 = *(const bf16x8*)(&Ps[wave][16 + l16][quad * 8]);
    bf16x8 ap11 = *(const bf16x8*)(&Ps[wave][16 + l16][32 + quad * 8]);
#pragma unroll
    for (int jd = 0; jd < 4; ++jd) {
      bf16x8 bv0 = *(const bf16x8*)(&Vts[jd * 16 + l16][quad * 8]);
      bf16x8 bv1 = *(const bf16x8*)(&Vts[jd * 16 + l16][32 + quad * 8]);
      o_acc[0][jd] = __builtin_amdgcn_mfma_f32_16x16x32_bf16(ap00, bv0, o_acc[0][jd], 0, 0, 0);
      o_acc[0][jd] = __builtin_amdgcn_mfma_f32_16x16x32_bf16(ap01, bv1, o_acc[0][jd], 0, 0, 0);
      o_acc[1][jd] = __builtin_amdgcn_mfma_f32_16x16x32_bf16(ap10, bv0, o_acc[1][jd], 0, 0, 0);
      o_acc[1][jd] = __builtin_amdgcn_mfma_f32_16x16x32_bf16(ap11, bv1, o_acc[1][jd], 0, 0, 0);
    }
    l_acc[0] = __builtin_amdgcn_mfma_f32_16x16x32_bf16(ap00, ones, l_acc[0], 0, 0, 0);
    l_acc[0] = __builtin_amdgcn_mfma_f32_16x16x32_bf16(ap01, ones, l_acc[0], 0, 0, 0);
    l_acc[1] = __builtin_amdgcn_mfma_f32_16x16x32_bf16(ap10, ones, l_acc[1], 0, 0, 0);
    l_acc[1] = __builtin_amdgcn_mfma_f32_16x16x32_bf16(ap11, ones, l_acc[1], 0, 0, 0);
  }

#pragma unroll
  for (int qs = 0; qs < 2; ++qs) {
#pragma unroll
    for (int r = 0; r < 4; ++r) {
      const int s = q0 + wave * 32 + qs * 16 + quad * 4 + r;
      const float inv = 1.f / l_acc[qs][r];
#pragma unroll
      for (int jd = 0; jd < 4; ++jd) {
        const int d = jd * 16 + l16;
        Oh[(size_t)(b * S_LEN + s) * D_MODEL + h * DEPTH + d] =
            (bf16)(o_acc[qs][jd][r] * inv);
      }
    }
  }
}

// ---------------------------------------------------------------- launch
extern "C" void kernel_launch(void* const* d_in, const int* in_sizes, int n_in,
                              void* d_out, int out_size, void* d_ws, size_t ws_size,
                              hipStream_t stream)
{
  const void* q    = d_in[0];
  const void* k    = d_in[1];
  const void* v    = d_in[2];
  const int*  mask = (const int*)d_in[3];
  const void* wq   = d_in[4];
  const void* bq   = d_in[5];
  const void* wk   = d_in[6];
  const void* bk   = d_in[7];
  const void* wv   = d_in[8];
  const void* bv   = d_in[9];
  const void* wo   = d_in[10];
  const void* bo   = d_in[11];

  char* ws = (char*)d_ws;
  const size_t MB = 1u << 20;
  bf16* Qh  = (bf16*)(ws + 0 * MB);    // [b,h,s,d]   8 MB (pre-scaled)
  bf16* Kc  = (bf16*)(ws + 8 * MB);    // [b,h,j,d]   8 MB compact
  bf16* Vc  = (bf16*)(ws + 16 * MB);   // [b,h,d,j]   8 MB compact
  bf16* Oh  = (bf16*)(ws + 24 * MB);   // [b,s,(h d)] 8 MB
  bf16* wqT = (bf16*)(ws + 32 * MB);
  bf16* wkT = (bf16*)(ws + 34 * MB);
  bf16* wvT = (bf16*)(ws + 36 * MB);
  bf16* woT = (bf16*)(ws + 38 * MB);
  bf16* bqb = (bf16*)(ws + 40 * MB);
  bf16* bkb = (bf16*)(ws + 40 * MB + 4096);
  bf16* bvb = (bf16*)(ws + 40 * MB + 8192);
  bf16* bob = (bf16*)(ws + 40 * MB + 12288);
  int*  flag = (int*)(ws + 40 * MB + 32768);
  int*  cpos = (int*)(ws + 40 * MB + 65536);           // 16 KB
  int*  nb   = (int*)(ws + 40 * MB + 65536 + 16384);   // 8 B
  bf16* qb  = (bf16*)(ws + 41 * MB);   // f32-conversion buffers (flag==0 only)
  bf16* kb_ = (bf16*)(ws + 49 * MB);
  bf16* vb_ = (bf16*)(ws + 57 * MB);

  probe_dtype<<<1, 64, 0, stream>>>((const uint32_t*)q, flag);
  scan_mask<<<2, 256, 0, stream>>>(mask, cpos, nb);

  prep_qkv<<<dim3(2048, 1, 3), 256, 0, stream>>>(q, k, v, qb, kb_, vb_, flag);
  prep_w<<<dim3(32, 32, 4), dim3(32, 8), 0, stream>>>(
      wq, wk, wv, wo, wqT, wkT, wvT, woT, flag);
  prep_bias<<<4, 256, 0, stream>>>(bq, bk, bv, bo, bqb, bkb, bvb, bob, flag);

  GArgs gq{qb,  q,  wqT, bqb, Qh, nullptr, 1};
  GArgs gk{kb_, k,  wkT, bkb, Kc, cpos,    3};
  GArgs gv{vb_, v,  wvT, bvb, Vc, cpos,    2};
  gemm_bt<<<dim3(8, 32, 3), 256, 0, stream>>>(gq, gk, gv, flag);

  attn<<<dim3(16, 32), 256, 0, stream>>>(Qh, Kc, Vc, nb, Oh);

  GArgs go{Oh, Oh, woT, bob, d_out, nullptr, 0};
  gemm_bt<<<dim3(8, 32, 1), 256, 0, stream>>>(go, go, go, flag);
}

// Round 6
// 232.820 us; speedup vs baseline: 1.3849x; 1.0347x over previous
//
#include <hip/hip_runtime.h>
#include <hip/hip_bf16.h>
#include <stdint.h>

// MultiHeadAttention: B=2, S=2048, D_MODEL=1024, H=16, depth=64.
// 4-launch pipeline (launch overhead ~11us/launch dominated the R5 profile):
//
//   1) setup (one launch, job ranges by blockIdx.x; every block probes the
//      input dtype locally from q's bit patterns — no cross-block dep):
//        [0,2)       mask scan     -> cpos[b][s] (-1 if masked), nb[b], flag
//        [2,6)       bias convert  -> bf16 (bq pre-scaled by 0.125*log2e)
//        [6,4102)    weight transpose -> bf16 W^T (wq pre-scaled)
//        [4102,10246) qkv f32->bf16 convert (early-out when already bf16)
//      Masked keys contribute exp(x-1e9) = +0 EXACTLY in fp32, so key
//      compaction is exact (~2x less attention work).
//   2) gemm_bt (z=3): projections -> Qh[b,h,s,d], Kc[b,h,j,d], Vc[b,h,d,j]
//      (K/V scattered to compact key index j=cpos[s])
//   3) attn: flash attention over compact keys, STATIC-max softmax
//      (exp2 domain; p=exp2(logit2-20), global 2^c factor cancels in o/l).
//      128 q-rows/block, 32 q-rows/wave (each K/V LDS read feeds 2 MFMAs).
//      Row sums l via ones-MFMA. Pad-tail keys killed by -30000 penalty.
//   4) gemm_bt (mode 0): Oh @ wo^T + bo -> out (bf16 or f32 per flag)

typedef __bf16 bf16;
typedef __bf16 bf16x8 __attribute__((ext_vector_type(8)));
typedef __bf16 bf16x4 __attribute__((ext_vector_type(4)));
typedef float  f32x4  __attribute__((ext_vector_type(4)));

#define D_MODEL 1024
#define S_LEN   2048
#define NH      16
#define DEPTH   64

#define LOG2E   1.4426950408889634f
#define QSCALE  (0.125f * LOG2E)     // folded into wq/bq at setup time
#define SMAX    20.0f                // static softmax max (log2 domain)
#define PADPEN  (-30000.0f)          // pad keys: exp2(~-30000) == +0 exactly

__device__ __forceinline__ void gload_lds16(const void* g, void* l) {
  __builtin_amdgcn_global_load_lds(
      (__attribute__((address_space(1))) void*)g,
      (__attribute__((address_space(3))) void*)l,
      16, 0, 0);
}

// ---------------------------------------------------------------- setup
// One launch for all prep. Every block locally detects the float dtype:
// word bits[14:7] = exponent of the low bf16 half; for bf16 data ~all of
// 256 samples land in [90,150]; for f32 (mantissa tail) ~61 do.
__global__ __launch_bounds__(256) void setup(
    const void* __restrict__ q, const void* __restrict__ k,
    const void* __restrict__ v, const int* __restrict__ mask,
    const void* __restrict__ wq, const void* __restrict__ wk,
    const void* __restrict__ wv, const void* __restrict__ wo,
    const void* __restrict__ bq, const void* __restrict__ bk,
    const void* __restrict__ bv, const void* __restrict__ bo,
    bf16* __restrict__ wqT, bf16* __restrict__ wkT,
    bf16* __restrict__ wvT, bf16* __restrict__ woT,
    bf16* __restrict__ bqb, bf16* __restrict__ bkb,
    bf16* __restrict__ bvb, bf16* __restrict__ bob,
    bf16* __restrict__ qb, bf16* __restrict__ kb, bf16* __restrict__ vb,
    int* __restrict__ cpos, int* __restrict__ nb, int* __restrict__ flagout)
{
  const int t = threadIdx.x;
  // local dtype probe (also acts as a block-wide barrier)
  {
    uint32_t w = ((const uint32_t*)q)[t];
    uint32_t e = (w >> 7) & 0xFF;
    int inr = (e >= 90 && e <= 150) ? 1 : 0;
    __shared__ int flg;
    int cnt = __syncthreads_count(inr);
    if (t == 0) flg = (cnt > 160) ? 1 : 0;
    __syncthreads();
    // broadcast via shared (cnt is uniform anyway, but be explicit)
    int flag = flg;

    const int bid = blockIdx.x;
    if (bid < 2) {
      // ---- mask scan for batch b = bid
      const int b = bid;
      const int lane = t & 63, wv4 = t >> 6;
      __shared__ int wsum[4];
      int vals[8], s = 0;
#pragma unroll
      for (int j = 0; j < 8; ++j) {
        vals[j] = (mask[b * S_LEN + t * 8 + j] == 0) ? 1 : 0;
        s += vals[j];
      }
      int acc = s;  // wave-inclusive scan
      for (int off = 1; off < 64; off <<= 1) {
        int u = __shfl_up(acc, off);
        if (lane >= off) acc += u;
      }
      if (lane == 63) wsum[wv4] = acc;
      __syncthreads();
      int base = 0;
      for (int w4 = 0; w4 < 4; ++w4) base += (w4 < wv4) ? wsum[w4] : 0;
      int ex = base + acc - s;
#pragma unroll
      for (int j = 0; j < 8; ++j) {
        cpos[b * S_LEN + t * 8 + j] = vals[j] ? ex : -1;
        ex += vals[j];
      }
      if (t == 255) nb[b] = base + acc;
      if (b == 0 && t == 0) *flagout = flag;
    } else if (bid < 6) {
      // ---- bias convert, job = bid-2
      const int j = bid - 2;
      const void* B; bf16* O;
      switch (j) {
        case 0:  B = bq; O = bqb; break;
        case 1:  B = bk; O = bkb; break;
        case 2:  B = bv; O = bvb; break;
        default: B = bo; O = bob; break;
      }
      const float sc = (j == 0) ? QSCALE : 1.0f;
      for (int jj = 0; jj < 4; ++jj) {
        const int i = t + jj * 256;
        const float val = flag ? (float)((const bf16*)B)[i] : ((const float*)B)[i];
        O[i] = (bf16)(val * sc);
      }
    } else if (bid < 6 + 4096) {
      // ---- weight transpose, job = bid-6: wsel = job>>10, tile = job&1023
      const int job = bid - 6;
      const int wsel = job >> 10, rem = job & 1023;
      const void* W; bf16* T;
      switch (wsel) {
        case 0:  W = wq; T = wqT; break;
        case 1:  W = wk; T = wkT; break;
        case 2:  W = wv; T = wvT; break;
        default: W = wo; T = woT; break;
      }
      const float sc = (wsel == 0) ? QSCALE : 1.0f;
      __shared__ float tile[32][33];
      const int tx = t & 31, ty = t >> 5;        // 32 x 8
      const int x0 = (rem & 31) * 32;            // col
      const int y0 = (rem >> 5) * 32;            // row
      for (int i = ty; i < 32; i += 8) {
        const size_t gi = (size_t)(y0 + i) * D_MODEL + x0 + tx;
        tile[i][tx] = flag ? (float)((const bf16*)W)[gi] : ((const float*)W)[gi];
      }
      __syncthreads();
      for (int i = ty; i < 32; i += 8)
        T[(size_t)(x0 + i) * D_MODEL + y0 + tx] = (bf16)(tile[tx][i] * sc);
    } else {
      // ---- qkv f32->bf16 convert (no-op when inputs already bf16)
      if (flag) return;
      const int job = bid - 4102;
      const int tensor = job >> 11, blk = job & 2047;
      const void* src; bf16* dst;
      switch (tensor) {
        case 0:  src = q; dst = qb; break;
        case 1:  src = k; dst = kb; break;
        default: src = v; dst = vb; break;
      }
      const size_t idx = ((size_t)blk * 256 + t) * 8;
      const float* s = (const float*)src + idx;
      f32x4 a = *(const f32x4*)(s);
      f32x4 b2 = *(const f32x4*)(s + 4);
      bf16x8 o;
      for (int i = 0; i < 4; ++i) { o[i] = (bf16)a[i]; o[4 + i] = (bf16)b2[i]; }
      *(bf16x8*)(dst + idx) = o;
    }
  }
}

// ---------------------------------------------------------------- GEMM A@B^T
// M=4096, N=1024, K=1024. 128x128 tile, 4 waves (2x2 of 64x64), BK=32.
struct GArgs {
  const bf16* A;     // converted A (used when flag==0)
  const void* Araw;  // original input (used as bf16 when flag==1)
  const bf16* BT;    // [1024][1024] bf16, row n = column n of W
  const bf16* bias;  // [1024] bf16
  void* out;
  const int* cpos;   // compact index per (b,s), modes 2/3 only
  int mode;          // 0: [m][n] per flag  1: Qh[b,h,s,d]
                     // 2: Vc[b,h,d,j] compact  3: Kc[b,h,j,d] compact
};

__global__ __launch_bounds__(256) void gemm_bt(GArgs g0, GArgs g1, GArgs g2,
                                               const int* __restrict__ flagp)
{
  GArgs g = (blockIdx.z == 0) ? g0 : ((blockIdx.z == 1) ? g1 : g2);
  const int flag = *flagp;
  const bf16* A = flag ? (const bf16*)g.Araw : g.A;

  __shared__ __align__(16) bf16 As[128 * 32];
  __shared__ __align__(16) bf16 Bs[128 * 32];
  const int tid  = threadIdx.x;
  const int wave = tid >> 6, lane = tid & 63;
  const int quad = lane >> 4, l16 = lane & 15;
  const int m0 = blockIdx.y * 128, n0 = blockIdx.x * 128;
  const int wm = (wave >> 1) * 64, wn = (wave & 1) * 64;
  const int srow = lane >> 2;
  const int scol = (lane & 3) * 8;

  f32x4 acc[4][4] = {};

  const bf16* Ag = A    + (size_t)(m0 + wave * 32 + srow) * D_MODEL + scol;
  const bf16* Bg = g.BT + (size_t)(n0 + wave * 32 + srow) * D_MODEL + scol;
  bf16* Asw = As + (wave * 32) * 32;   // wave-uniform LDS base
  bf16* Bsw = Bs + (wave * 32) * 32;

  for (int kt = 0; kt < D_MODEL; kt += 32) {
    __syncthreads();
    gload_lds16(Ag + kt,                Asw);
    gload_lds16(Ag + kt + 16 * D_MODEL, Asw + 16 * 32);
    gload_lds16(Bg + kt,                Bsw);
    gload_lds16(Bg + kt + 16 * D_MODEL, Bsw + 16 * 32);
    __syncthreads();

    bf16x8 af[4], bfv[4];
#pragma unroll
    for (int mi = 0; mi < 4; ++mi)
      af[mi] = *(const bf16x8*)(As + (wm + mi * 16 + l16) * 32 + quad * 8);
#pragma unroll
    for (int ni = 0; ni < 4; ++ni)
      bfv[ni] = *(const bf16x8*)(Bs + (wn + ni * 16 + l16) * 32 + quad * 8);
#pragma unroll
    for (int mi = 0; mi < 4; ++mi)
#pragma unroll
      for (int ni = 0; ni < 4; ++ni)
        acc[mi][ni] = __builtin_amdgcn_mfma_f32_16x16x32_bf16(
            af[mi], bfv[ni], acc[mi][ni], 0, 0, 0);
  }

  // C layout: row = quad*4 + r, col = l16 (m89-verified)
#pragma unroll
  for (int mi = 0; mi < 4; ++mi) {
    const int row0 = m0 + wm + mi * 16 + quad * 4;
    const int b = row0 >> 11, s = row0 & 2047;
    int cp[4];
    if (g.mode >= 2) {
#pragma unroll
      for (int r = 0; r < 4; ++r) cp[r] = g.cpos[b * S_LEN + s + r];
    }
#pragma unroll
    for (int ni = 0; ni < 4; ++ni) {
      const int col  = n0 + wn + ni * 16 + l16;
      const float bv = (float)g.bias[col];
      const int hh = col >> 6, d = col & 63;
      if (g.mode == 3) {          // Kc[b,h,j,d]
        bf16* base = (bf16*)g.out + (size_t)(b * NH + hh) * S_LEN * DEPTH + d;
#pragma unroll
        for (int r = 0; r < 4; ++r)
          if (cp[r] >= 0) base[(size_t)cp[r] * DEPTH] = (bf16)(acc[mi][ni][r] + bv);
      } else if (g.mode == 2) {   // Vc[b,h,d,j]
        bf16* base = (bf16*)g.out + ((size_t)(b * NH + hh) * DEPTH + d) * S_LEN;
#pragma unroll
        for (int r = 0; r < 4; ++r)
          if (cp[r] >= 0) base[cp[r]] = (bf16)(acc[mi][ni][r] + bv);
      } else if (g.mode == 1) {   // Qh[b,h,s,d]
        bf16* op = (bf16*)g.out + ((size_t)(b * NH + hh) * S_LEN + s) * DEPTH + d;
#pragma unroll
        for (int r = 0; r < 4; ++r)
          op[(size_t)r * DEPTH] = (bf16)(acc[mi][ni][r] + bv);
      } else {
        if (flag) {
          bf16* op = (bf16*)g.out + (size_t)row0 * D_MODEL + col;
#pragma unroll
          for (int r = 0; r < 4; ++r)
            op[(size_t)r * D_MODEL] = (bf16)(acc[mi][ni][r] + bv);
        } else {
          float* op = (float*)g.out + (size_t)row0 * D_MODEL + col;
#pragma unroll
          for (int r = 0; r < 4; ++r)
            op[(size_t)r * D_MODEL] = acc[mi][ni][r] + bv;
        }
      }
    }
  }
}

// ---------------------------------------------------------------- attention
// grid (16 q-tiles, 32 bh), 256 thr = 4 waves; wave w owns q-rows
// [q0+w*32, +32) as two 16-row sub-tiles. Keys: compacted, 64-key blocks up
// to nb_pad. Static-max softmax; pad keys killed by -30000 penalty.
__global__ __launch_bounds__(256) void attn(
    const bf16* __restrict__ Qh, const bf16* __restrict__ Kc,
    const bf16* __restrict__ Vc, const int* __restrict__ nbp,
    bf16* __restrict__ Oh)
{
  const int bh = blockIdx.y;
  const int b  = bh >> 4;
  const int h  = bh & 15;
  const int q0 = blockIdx.x * 128;
  const int tid = threadIdx.x, wave = tid >> 6, lane = tid & 63;
  const int quad = lane >> 4, l16 = lane & 15;

  __shared__ __align__(16) bf16 Ks[64][72];
  __shared__ __align__(16) bf16 Vts[64][72];    // [d][j']
  __shared__ __align__(16) bf16 Ps[4][32][72];  // per-wave P tile

  const int nbv = nbp[b];
  const int nb_pad = (nbv + 63) & ~63;

  // Q fragments straight from global (Q is pre-scaled by QSCALE)
  const bf16* Qg = Qh + ((size_t)bh * S_LEN + q0 + wave * 32) * DEPTH;
  bf16x8 aq00 = *(const bf16x8*)(Qg + (size_t)l16 * DEPTH + quad * 8);
  bf16x8 aq01 = *(const bf16x8*)(Qg + (size_t)l16 * DEPTH + 32 + quad * 8);
  bf16x8 aq10 = *(const bf16x8*)(Qg + (size_t)(16 + l16) * DEPTH + quad * 8);
  bf16x8 aq11 = *(const bf16x8*)(Qg + (size_t)(16 + l16) * DEPTH + 32 + quad * 8);

  bf16x8 ones;
#pragma unroll
  for (int j = 0; j < 8; ++j) ones[j] = (bf16)1.0f;

  f32x4 o_acc[2][4] = {};
  f32x4 l_acc[2] = {};

  const bf16* Kg = Kc + (size_t)bh * S_LEN * DEPTH;
  const bf16* Vg = Vc + (size_t)bh * DEPTH * S_LEN;

  for (int kb = 0; kb < nb_pad; kb += 64) {
    __syncthreads();
    for (int i = tid; i < 512; i += 256) {
      int r = i >> 3, c = (i & 7) * 8;
      *(bf16x8*)(&Ks[r][c])  = *(const bf16x8*)(Kg + (size_t)(kb + r) * DEPTH + c);
      *(bf16x8*)(&Vts[r][c]) = *(const bf16x8*)(Vg + (size_t)r * S_LEN + kb + c);
    }
    __syncthreads();

    // S = Q K^T : 32 q-rows x 64 keys; each bk pair feeds both q sub-tiles
    f32x4 sacc[2][4] = {};
#pragma unroll
    for (int jn = 0; jn < 4; ++jn) {
      bf16x8 bk0 = *(const bf16x8*)(&Ks[jn * 16 + l16][quad * 8]);
      bf16x8 bk1 = *(const bf16x8*)(&Ks[jn * 16 + l16][32 + quad * 8]);
      sacc[0][jn] = __builtin_amdgcn_mfma_f32_16x16x32_bf16(aq00, bk0, sacc[0][jn], 0, 0, 0);
      sacc[0][jn] = __builtin_amdgcn_mfma_f32_16x16x32_bf16(aq01, bk1, sacc[0][jn], 0, 0, 0);
      sacc[1][jn] = __builtin_amdgcn_mfma_f32_16x16x32_bf16(aq10, bk0, sacc[1][jn], 0, 0, 0);
      sacc[1][jn] = __builtin_amdgcn_mfma_f32_16x16x32_bf16(aq11, bk1, sacc[1][jn], 0, 0, 0);
    }

    // p = exp2(s - SMAX), pad keys -> exactly 0
#pragma unroll
    for (int jn = 0; jn < 4; ++jn) {
      const int key = kb + jn * 16 + l16;
      const float pen = (key < nbv) ? (-SMAX) : PADPEN;
#pragma unroll
      for (int qs = 0; qs < 2; ++qs)
#pragma unroll
        for (int r = 0; r < 4; ++r)
          Ps[wave][qs * 16 + quad * 4 + r][jn * 16 + l16] =
              (bf16)__builtin_amdgcn_exp2f(sacc[qs][jn][r] + pen);
    }

    // O += P @ V ; l += P @ 1  (Ps same-wave write->read: DS in-order)
    bf16x8 ap00 = *(const bf16x8*)(&Ps[wave][l16][quad * 8]);
    bf16x8 ap01 = *(const bf16x8*)(&Ps[wave][l16][32 + quad * 8]);
    bf16x8 ap10 = *(const bf16x8*)(&Ps[wave][16 + l16][quad * 8]);
    bf16x8 ap11 = *(const bf16x8*)(&Ps[wave][16 + l16][32 + quad * 8]);
#pragma unroll
    for (int jd = 0; jd < 4; ++jd) {
      bf16x8 bv0 = *(const bf16x8*)(&Vts[jd * 16 + l16][quad * 8]);
      bf16x8 bv1 = *(const bf16x8*)(&Vts[jd * 16 + l16][32 + quad * 8]);
      o_acc[0][jd] = __builtin_amdgcn_mfma_f32_16x16x32_bf16(ap00, bv0, o_acc[0][jd], 0, 0, 0);
      o_acc[0][jd] = __builtin_amdgcn_mfma_f32_16x16x32_bf16(ap01, bv1, o_acc[0][jd], 0, 0, 0);
      o_acc[1][jd] = __builtin_amdgcn_mfma_f32_16x16x32_bf16(ap10, bv0, o_acc[1][jd], 0, 0, 0);
      o_acc[1][jd] = __builtin_amdgcn_mfma_f32_16x16x32_bf16(ap11, bv1, o_acc[1][jd], 0, 0, 0);
    }
    l_acc[0] = __builtin_amdgcn_mfma_f32_16x16x32_bf16(ap00, ones, l_acc[0], 0, 0, 0);
    l_acc[0] = __builtin_amdgcn_mfma_f32_16x16x32_bf16(ap01, ones, l_acc[0], 0, 0, 0);
    l_acc[1] = __builtin_amdgcn_mfma_f32_16x16x32_bf16(ap10, ones, l_acc[1], 0, 0, 0);
    l_acc[1] = __builtin_amdgcn_mfma_f32_16x16x32_bf16(ap11, ones, l_acc[1], 0, 0, 0);
  }

#pragma unroll
  for (int qs = 0; qs < 2; ++qs) {
#pragma unroll
    for (int r = 0; r < 4; ++r) {
      const int s = q0 + wave * 32 + qs * 16 + quad * 4 + r;
      const float inv = 1.f / l_acc[qs][r];
#pragma unroll
      for (int jd = 0; jd < 4; ++jd) {
        const int d = jd * 16 + l16;
        Oh[(size_t)(b * S_LEN + s) * D_MODEL + h * DEPTH + d] =
            (bf16)(o_acc[qs][jd][r] * inv);
      }
    }
  }
}

// ---------------------------------------------------------------- launch
extern "C" void kernel_launch(void* const* d_in, const int* in_sizes, int n_in,
                              void* d_out, int out_size, void* d_ws, size_t ws_size,
                              hipStream_t stream)
{
  const void* q    = d_in[0];
  const void* k    = d_in[1];
  const void* v    = d_in[2];
  const int*  mask = (const int*)d_in[3];
  const void* wq   = d_in[4];
  const void* bq   = d_in[5];
  const void* wk   = d_in[6];
  const void* bk   = d_in[7];
  const void* wv   = d_in[8];
  const void* bv   = d_in[9];
  const void* wo   = d_in[10];
  const void* bo   = d_in[11];

  char* ws = (char*)d_ws;
  const size_t MB = 1u << 20;
  bf16* Qh  = (bf16*)(ws + 0 * MB);    // [b,h,s,d]   8 MB (pre-scaled)
  bf16* Kc  = (bf16*)(ws + 8 * MB);    // [b,h,j,d]   8 MB compact
  bf16* Vc  = (bf16*)(ws + 16 * MB);   // [b,h,d,j]   8 MB compact
  bf16* Oh  = (bf16*)(ws + 24 * MB);   // [b,s,(h d)] 8 MB
  bf16* wqT = (bf16*)(ws + 32 * MB);
  bf16* wkT = (bf16*)(ws + 34 * MB);
  bf16* wvT = (bf16*)(ws + 36 * MB);
  bf16* woT = (bf16*)(ws + 38 * MB);
  bf16* bqb = (bf16*)(ws + 40 * MB);
  bf16* bkb = (bf16*)(ws + 40 * MB + 4096);
  bf16* bvb = (bf16*)(ws + 40 * MB + 8192);
  bf16* bob = (bf16*)(ws + 40 * MB + 12288);
  int*  flag = (int*)(ws + 40 * MB + 32768);
  int*  cpos = (int*)(ws + 40 * MB + 65536);           // 16 KB
  int*  nb   = (int*)(ws + 40 * MB + 65536 + 16384);   // 8 B
  bf16* qb  = (bf16*)(ws + 41 * MB);   // f32-conversion buffers (flag==0 only)
  bf16* kb_ = (bf16*)(ws + 49 * MB);
  bf16* vb_ = (bf16*)(ws + 57 * MB);

  setup<<<10246, 256, 0, stream>>>(
      q, k, v, mask, wq, wk, wv, wo, bq, bk, bv, bo,
      wqT, wkT, wvT, woT, bqb, bkb, bvb, bob,
      qb, kb_, vb_, cpos, nb, flag);

  GArgs gq{qb,  q,  wqT, bqb, Qh, nullptr, 1};
  GArgs gk{kb_, k,  wkT, bkb, Kc, cpos,    3};
  GArgs gv{vb_, v,  wvT, bvb, Vc, cpos,    2};
  gemm_bt<<<dim3(8, 32, 3), 256, 0, stream>>>(gq, gk, gv, flag);

  attn<<<dim3(16, 32), 256, 0, stream>>>(Qh, Kc, Vc, nb, Oh);

  GArgs go{Oh, Oh, woT, bob, d_out, nullptr, 0};
  gemm_bt<<<dim3(8, 32, 1), 256, 0, stream>>>(go, go, go, flag);
}

// Round 7
// 229.754 us; speedup vs baseline: 1.4033x; 1.0133x over previous
//
#include <hip/hip_runtime.h>
#include <hip/hip_bf16.h>
#include <stdint.h>

// MultiHeadAttention: B=2, S=2048, D_MODEL=1024, H=16, depth=64.
// 4-launch pipeline. ~110us/iter is fixed harness restore/poison overhead
// (constant across 9-launch R5 and 4-launch R6); kernel sum is the budget.
//
//   1) setup: dtype probe per block (f32 vs bf16), mask scan->cpos/nb,
//      bias convert, weight transpose (wq,bq pre-scaled by 0.125*log2e),
//      qkv f32->bf16 convert. Masked keys contribute exp(x-1e9)=+0 EXACTLY
//      in fp32 -> key compaction is exact (~2x less attention work).
//   2) gemm_qkv (z=3): projections -> Qh[b,h,s,d], Kc[b,h,j,d], Vc[b,h,d,j]
//      XCD-swizzled block mapping (4x8 rectangles) for A-panel L2 reuse.
//   3) attn: flash attention over compact keys, STATIC-max softmax
//      (exp2 domain), 32 q-rows/wave, K/V global->reg prefetch pipeline.
//   4) gemm_out: Oh @ wo^T + bo -> out (bf16 or f32 per flag)

typedef __bf16 bf16;
typedef __bf16 bf16x8 __attribute__((ext_vector_type(8)));
typedef __bf16 bf16x4 __attribute__((ext_vector_type(4)));
typedef float  f32x4  __attribute__((ext_vector_type(4)));

#define D_MODEL 1024
#define S_LEN   2048
#define NH      16
#define DEPTH   64

#define LOG2E   1.4426950408889634f
#define QSCALE  (0.125f * LOG2E)     // folded into wq/bq at setup time
#define SMAX    20.0f                // static softmax max (log2 domain)
#define PADPEN  (-30000.0f)          // pad keys: exp2(~-30000) == +0 exactly

__device__ __forceinline__ void gload_lds16(const void* g, void* l) {
  __builtin_amdgcn_global_load_lds(
      (__attribute__((address_space(1))) void*)g,
      (__attribute__((address_space(3))) void*)l,
      16, 0, 0);
}

// ---------------------------------------------------------------- setup
__global__ __launch_bounds__(256) void setup(
    const void* __restrict__ q, const void* __restrict__ k,
    const void* __restrict__ v, const int* __restrict__ mask,
    const void* __restrict__ wq, const void* __restrict__ wk,
    const void* __restrict__ wv, const void* __restrict__ wo,
    const void* __restrict__ bq, const void* __restrict__ bk,
    const void* __restrict__ bv, const void* __restrict__ bo,
    bf16* __restrict__ wqT, bf16* __restrict__ wkT,
    bf16* __restrict__ wvT, bf16* __restrict__ woT,
    bf16* __restrict__ bqb, bf16* __restrict__ bkb,
    bf16* __restrict__ bvb, bf16* __restrict__ bob,
    bf16* __restrict__ qb, bf16* __restrict__ kb, bf16* __restrict__ vb,
    int* __restrict__ cpos, int* __restrict__ nb, int* __restrict__ flagout)
{
  const int t = threadIdx.x;
  // local dtype probe: word bits[14:7] = exponent of low bf16 half;
  // bf16 data -> ~all of 256 samples in [90,150]; f32 mantissa tail -> ~61.
  uint32_t w = ((const uint32_t*)q)[t];
  uint32_t e = (w >> 7) & 0xFF;
  int inr = (e >= 90 && e <= 150) ? 1 : 0;
  __shared__ int flg;
  int cnt = __syncthreads_count(inr);
  if (t == 0) flg = (cnt > 160) ? 1 : 0;
  __syncthreads();
  int flag = flg;

  const int bid = blockIdx.x;
  if (bid < 2) {
    // ---- mask scan for batch b = bid
    const int b = bid;
    const int lane = t & 63, wv4 = t >> 6;
    __shared__ int wsum[4];
    int vals[8], s = 0;
#pragma unroll
    for (int j = 0; j < 8; ++j) {
      vals[j] = (mask[b * S_LEN + t * 8 + j] == 0) ? 1 : 0;
      s += vals[j];
    }
    int acc = s;  // wave-inclusive scan
    for (int off = 1; off < 64; off <<= 1) {
      int u = __shfl_up(acc, off);
      if (lane >= off) acc += u;
    }
    if (lane == 63) wsum[wv4] = acc;
    __syncthreads();
    int base = 0;
    for (int w4 = 0; w4 < 4; ++w4) base += (w4 < wv4) ? wsum[w4] : 0;
    int ex = base + acc - s;
#pragma unroll
    for (int j = 0; j < 8; ++j) {
      cpos[b * S_LEN + t * 8 + j] = vals[j] ? ex : -1;
      ex += vals[j];
    }
    if (t == 255) nb[b] = base + acc;
    if (b == 0 && t == 0) *flagout = flag;
  } else if (bid < 6) {
    // ---- bias convert, job = bid-2
    const int j = bid - 2;
    const void* B; bf16* O;
    switch (j) {
      case 0:  B = bq; O = bqb; break;
      case 1:  B = bk; O = bkb; break;
      case 2:  B = bv; O = bvb; break;
      default: B = bo; O = bob; break;
    }
    const float sc = (j == 0) ? QSCALE : 1.0f;
    for (int jj = 0; jj < 4; ++jj) {
      const int i = t + jj * 256;
      const float val = flag ? (float)((const bf16*)B)[i] : ((const float*)B)[i];
      O[i] = (bf16)(val * sc);
    }
  } else if (bid < 6 + 4096) {
    // ---- weight transpose, job = bid-6
    const int job = bid - 6;
    const int wsel = job >> 10, rem = job & 1023;
    const void* W; bf16* T;
    switch (wsel) {
      case 0:  W = wq; T = wqT; break;
      case 1:  W = wk; T = wkT; break;
      case 2:  W = wv; T = wvT; break;
      default: W = wo; T = woT; break;
    }
    const float sc = (wsel == 0) ? QSCALE : 1.0f;
    __shared__ float tile[32][33];
    const int tx = t & 31, ty = t >> 5;        // 32 x 8
    const int x0 = (rem & 31) * 32;            // col
    const int y0 = (rem >> 5) * 32;            // row
    for (int i = ty; i < 32; i += 8) {
      const size_t gi = (size_t)(y0 + i) * D_MODEL + x0 + tx;
      tile[i][tx] = flag ? (float)((const bf16*)W)[gi] : ((const float*)W)[gi];
    }
    __syncthreads();
    for (int i = ty; i < 32; i += 8)
      T[(size_t)(x0 + i) * D_MODEL + y0 + tx] = (bf16)(tile[tx][i] * sc);
  } else {
    // ---- qkv f32->bf16 convert (no-op when inputs already bf16)
    if (flag) return;
    const int job = bid - 4102;
    const int tensor = job >> 11, blk = job & 2047;
    const void* src; bf16* dst;
    switch (tensor) {
      case 0:  src = q; dst = qb; break;
      case 1:  src = k; dst = kb; break;
      default: src = v; dst = vb; break;
    }
    const size_t idx = ((size_t)blk * 256 + t) * 8;
    const float* s = (const float*)src + idx;
    f32x4 a = *(const f32x4*)(s);
    f32x4 b2 = *(const f32x4*)(s + 4);
    bf16x8 o;
    for (int i = 0; i < 4; ++i) { o[i] = (bf16)a[i]; o[4 + i] = (bf16)b2[i]; }
    *(bf16x8*)(dst + idx) = o;
  }
}

// ---------------------------------------------------------------- GEMM A@B^T
// M=4096, N=1024, K=1024. 128x128 tile, 4 waves (2x2 of 64x64), BK=32.
// Block (x,y) XCD-swizzled: assuming XCD = flat%8 round-robin, each XCD gets
// a 4(x) x 8(y) rectangle -> A row-panel fetched by 2 XCDs instead of 8.
struct GArgs {
  const bf16* A;     // converted A (used when flag==0)
  const void* Araw;  // original input (used as bf16 when flag==1)
  const bf16* BT;    // [1024][1024] bf16, row n = column n of W
  const bf16* bias;  // [1024] bf16
  void* out;
  const int* cpos;   // compact index per (b,s), modes 2/3 only
  int mode;          // 0: [m][n] per flag  1: Qh[b,h,s,d]
                     // 2: Vc[b,h,d,j] compact  3: Kc[b,h,j,d] compact
};

__device__ __forceinline__ void gemm_body(const GArgs& g, int flag)
{
  const bf16* A = flag ? (const bf16*)g.Araw : g.A;

  __shared__ __align__(16) bf16 As[128 * 32];
  __shared__ __align__(16) bf16 Bs[128 * 32];
  const int tid  = threadIdx.x;
  const int wave = tid >> 6, lane = tid & 63;
  const int quad = lane >> 4, l16 = lane & 15;

  // XCD swizzle (8 x-tiles, 32 y-tiles per z-slice)
  const int flat = blockIdx.y * 8 + blockIdx.x;
  const int xcd = flat & 7, pos = flat >> 3;           // pos 0..31
  const int bx = (xcd & 1) * 4 + (pos & 3);
  const int by = (xcd >> 1) * 8 + (pos >> 2);
  const int m0 = by * 128, n0 = bx * 128;

  const int wm = (wave >> 1) * 64, wn = (wave & 1) * 64;
  const int srow = lane >> 2;
  const int scol = (lane & 3) * 8;

  f32x4 acc[4][4] = {};

  const bf16* Ag = A    + (size_t)(m0 + wave * 32 + srow) * D_MODEL + scol;
  const bf16* Bg = g.BT + (size_t)(n0 + wave * 32 + srow) * D_MODEL + scol;
  bf16* Asw = As + (wave * 32) * 32;   // wave-uniform LDS base
  bf16* Bsw = Bs + (wave * 32) * 32;

  for (int kt = 0; kt < D_MODEL; kt += 32) {
    __syncthreads();
    gload_lds16(Ag + kt,                Asw);
    gload_lds16(Ag + kt + 16 * D_MODEL, Asw + 16 * 32);
    gload_lds16(Bg + kt,                Bsw);
    gload_lds16(Bg + kt + 16 * D_MODEL, Bsw + 16 * 32);
    __syncthreads();

    bf16x8 af[4], bfv[4];
#pragma unroll
    for (int mi = 0; mi < 4; ++mi)
      af[mi] = *(const bf16x8*)(As + (wm + mi * 16 + l16) * 32 + quad * 8);
#pragma unroll
    for (int ni = 0; ni < 4; ++ni)
      bfv[ni] = *(const bf16x8*)(Bs + (wn + ni * 16 + l16) * 32 + quad * 8);
#pragma unroll
    for (int mi = 0; mi < 4; ++mi)
#pragma unroll
      for (int ni = 0; ni < 4; ++ni)
        acc[mi][ni] = __builtin_amdgcn_mfma_f32_16x16x32_bf16(
            af[mi], bfv[ni], acc[mi][ni], 0, 0, 0);
  }

  // C layout: row = quad*4 + r, col = l16 (m89-verified)
#pragma unroll
  for (int mi = 0; mi < 4; ++mi) {
    const int row0 = m0 + wm + mi * 16 + quad * 4;
    const int b = row0 >> 11, s = row0 & 2047;
    int cp[4];
    if (g.mode >= 2) {
#pragma unroll
      for (int r = 0; r < 4; ++r) cp[r] = g.cpos[b * S_LEN + s + r];
    }
#pragma unroll
    for (int ni = 0; ni < 4; ++ni) {
      const int col  = n0 + wn + ni * 16 + l16;
      const float bv = (float)g.bias[col];
      const int hh = col >> 6, d = col & 63;
      if (g.mode == 3) {          // Kc[b,h,j,d]
        bf16* base = (bf16*)g.out + (size_t)(b * NH + hh) * S_LEN * DEPTH + d;
#pragma unroll
        for (int r = 0; r < 4; ++r)
          if (cp[r] >= 0) base[(size_t)cp[r] * DEPTH] = (bf16)(acc[mi][ni][r] + bv);
      } else if (g.mode == 2) {   // Vc[b,h,d,j]
        bf16* base = (bf16*)g.out + ((size_t)(b * NH + hh) * DEPTH + d) * S_LEN;
#pragma unroll
        for (int r = 0; r < 4; ++r)
          if (cp[r] >= 0) base[cp[r]] = (bf16)(acc[mi][ni][r] + bv);
      } else if (g.mode == 1) {   // Qh[b,h,s,d]
        bf16* op = (bf16*)g.out + ((size_t)(b * NH + hh) * S_LEN + s) * DEPTH + d;
#pragma unroll
        for (int r = 0; r < 4; ++r)
          op[(size_t)r * DEPTH] = (bf16)(acc[mi][ni][r] + bv);
      } else {
        if (flag) {
          bf16* op = (bf16*)g.out + (size_t)row0 * D_MODEL + col;
#pragma unroll
          for (int r = 0; r < 4; ++r)
            op[(size_t)r * D_MODEL] = (bf16)(acc[mi][ni][r] + bv);
        } else {
          float* op = (float*)g.out + (size_t)row0 * D_MODEL + col;
#pragma unroll
          for (int r = 0; r < 4; ++r)
            op[(size_t)r * D_MODEL] = acc[mi][ni][r] + bv;
        }
      }
    }
  }
}

__global__ __launch_bounds__(256) void gemm_qkv(GArgs g0, GArgs g1, GArgs g2,
                                                const int* __restrict__ flagp)
{
  const GArgs& g = (blockIdx.z == 0) ? g0 : ((blockIdx.z == 1) ? g1 : g2);
  gemm_body(g, *flagp);
}

__global__ __launch_bounds__(256) void gemm_out(GArgs g,
                                                const int* __restrict__ flagp)
{
  gemm_body(g, *flagp);
}

// ---------------------------------------------------------------- attention
// grid (16 q-tiles, 32 bh), 256 thr = 4 waves; wave w owns q-rows
// [q0+w*32, +32) as two 16-row sub-tiles. Compact keys, 64-key blocks.
// Static-max softmax; pad keys killed by -30000 penalty. K/V tiles are
// prefetched to registers one block ahead (global latency overlaps compute).
__global__ __launch_bounds__(256) void attn(
    const bf16* __restrict__ Qh, const bf16* __restrict__ Kc,
    const bf16* __restrict__ Vc, const int* __restrict__ nbp,
    bf16* __restrict__ Oh)
{
  const int bh = blockIdx.y;
  const int b  = bh >> 4;
  const int h  = bh & 15;
  const int q0 = blockIdx.x * 128;
  const int tid = threadIdx.x, wave = tid >> 6, lane = tid & 63;
  const int quad = lane >> 4, l16 = lane & 15;

  __shared__ __align__(16) bf16 Ks[64][72];
  __shared__ __align__(16) bf16 Vts[64][72];    // [d][j']
  __shared__ __align__(16) bf16 Ps[4][32][72];  // per-wave P tile

  const int nbv = nbp[b];
  const int nb_pad = (nbv + 63) & ~63;

  // Q fragments straight from global (Q is pre-scaled by QSCALE)
  const bf16* Qg = Qh + ((size_t)bh * S_LEN + q0 + wave * 32) * DEPTH;
  bf16x8 aq00 = *(const bf16x8*)(Qg + (size_t)l16 * DEPTH + quad * 8);
  bf16x8 aq01 = *(const bf16x8*)(Qg + (size_t)l16 * DEPTH + 32 + quad * 8);
  bf16x8 aq10 = *(const bf16x8*)(Qg + (size_t)(16 + l16) * DEPTH + quad * 8);
  bf16x8 aq11 = *(const bf16x8*)(Qg + (size_t)(16 + l16) * DEPTH + 32 + quad * 8);

  bf16x8 ones;
#pragma unroll
  for (int j = 0; j < 8; ++j) ones[j] = (bf16)1.0f;

  f32x4 o_acc[2][4] = {};
  f32x4 l_acc[2] = {};

  const bf16* Kg = Kc + (size_t)bh * S_LEN * DEPTH;
  const bf16* Vg = Vc + (size_t)bh * DEPTH * S_LEN;

  // staging coords: thread covers rows sr0 and sr1 (=sr0+32), 8 cols each
  const int sr0 = tid >> 3, sc0 = (tid & 7) * 8;
  const int sr1 = sr0 + 32;

  bf16x8 kr0, kr1, vr0, vr1;
  {
    kr0 = *(const bf16x8*)(Kg + (size_t)sr0 * DEPTH + sc0);
    kr1 = *(const bf16x8*)(Kg + (size_t)sr1 * DEPTH + sc0);
    vr0 = *(const bf16x8*)(Vg + (size_t)sr0 * S_LEN + sc0);
    vr1 = *(const bf16x8*)(Vg + (size_t)sr1 * S_LEN + sc0);
  }

  for (int kb = 0; kb < nb_pad; kb += 64) {
    __syncthreads();                       // previous tile fully consumed
    *(bf16x8*)(&Ks[sr0][sc0])  = kr0;
    *(bf16x8*)(&Ks[sr1][sc0])  = kr1;
    *(bf16x8*)(&Vts[sr0][sc0]) = vr0;
    *(bf16x8*)(&Vts[sr1][sc0]) = vr1;
    __syncthreads();                       // tile published
    if (kb + 64 < nb_pad) {                // prefetch next (overlaps compute)
      kr0 = *(const bf16x8*)(Kg + (size_t)(kb + 64 + sr0) * DEPTH + sc0);
      kr1 = *(const bf16x8*)(Kg + (size_t)(kb + 64 + sr1) * DEPTH + sc0);
      vr0 = *(const bf16x8*)(Vg + (size_t)sr0 * S_LEN + kb + 64 + sc0);
      vr1 = *(const bf16x8*)(Vg + (size_t)sr1 * S_LEN + kb + 64 + sc0);
    }

    // S = Q K^T : 32 q-rows x 64 keys; each bk pair feeds both q sub-tiles
    f32x4 sacc[2][4] = {};
#pragma unroll
    for (int jn = 0; jn < 4; ++jn) {
      bf16x8 bk0 = *(const bf16x8*)(&Ks[jn * 16 + l16][quad * 8]);
      bf16x8 bk1 = *(const bf16x8*)(&Ks[jn * 16 + l16][32 + quad * 8]);
      sacc[0][jn] = __builtin_amdgcn_mfma_f32_16x16x32_bf16(aq00, bk0, sacc[0][jn], 0, 0, 0);
      sacc[0][jn] = __builtin_amdgcn_mfma_f32_16x16x32_bf16(aq01, bk1, sacc[0][jn], 0, 0, 0);
      sacc[1][jn] = __builtin_amdgcn_mfma_f32_16x16x32_bf16(aq10, bk0, sacc[1][jn], 0, 0, 0);
      sacc[1][jn] = __builtin_amdgcn_mfma_f32_16x16x32_bf16(aq11, bk1, sacc[1][jn], 0, 0, 0);
    }

    // p = exp2(s - SMAX), pad keys -> exactly 0
#pragma unroll
    for (int jn = 0; jn < 4; ++jn) {
      const int key = kb + jn * 16 + l16;
      const float pen = (key < nbv) ? (-SMAX) : PADPEN;
#pragma unroll
      for (int qs = 0; qs < 2; ++qs)
#pragma unroll
        for (int r = 0; r < 4; ++r)
          Ps[wave][qs * 16 + quad * 4 + r][jn * 16 + l16] =
              (bf16)__builtin_amdgcn_exp2f(sacc[qs][jn][r] + pen);
    }

    // O += P @ V ; l += P @ 1  (Ps same-wave write->read: DS in-order)
    bf16x8 ap00 = *(const bf16x8*)(&Ps[wave][l16][quad * 8]);
    bf16x8 ap01 = *(const bf16x8*)(&Ps[wave][l16][32 + quad * 8]);
    bf16x8 ap10 = *(const bf16x8*)(&Ps[wave][16 + l16][quad * 8]);
    bf16x8 ap11 = *(const bf16x8*)(&Ps[wave][16 + l16][32 + quad * 8]);
#pragma unroll
    for (int jd = 0; jd < 4; ++jd) {
      bf16x8 bv0 = *(const bf16x8*)(&Vts[jd * 16 + l16][quad * 8]);
      bf16x8 bv1 = *(const bf16x8*)(&Vts[jd * 16 + l16][32 + quad * 8]);
      o_acc[0][jd] = __builtin_amdgcn_mfma_f32_16x16x32_bf16(ap00, bv0, o_acc[0][jd], 0, 0, 0);
      o_acc[0][jd] = __builtin_amdgcn_mfma_f32_16x16x32_bf16(ap01, bv1, o_acc[0][jd], 0, 0, 0);
      o_acc[1][jd] = __builtin_amdgcn_mfma_f32_16x16x32_bf16(ap10, bv0, o_acc[1][jd], 0, 0, 0);
      o_acc[1][jd] = __builtin_amdgcn_mfma_f32_16x16x32_bf16(ap11, bv1, o_acc[1][jd], 0, 0, 0);
    }
    l_acc[0] = __builtin_amdgcn_mfma_f32_16x16x32_bf16(ap00, ones, l_acc[0], 0, 0, 0);
    l_acc[0] = __builtin_amdgcn_mfma_f32_16x16x32_bf16(ap01, ones, l_acc[0], 0, 0, 0);
    l_acc[1] = __builtin_amdgcn_mfma_f32_16x16x32_bf16(ap10, ones, l_acc[1], 0, 0, 0);
    l_acc[1] = __builtin_amdgcn_mfma_f32_16x16x32_bf16(ap11, ones, l_acc[1], 0, 0, 0);
  }

#pragma unroll
  for (int qs = 0; qs < 2; ++qs) {
#pragma unroll
    for (int r = 0; r < 4; ++r) {
      const int s = q0 + wave * 32 + qs * 16 + quad * 4 + r;
      const float inv = 1.f / l_acc[qs][r];
#pragma unroll
      for (int jd = 0; jd < 4; ++jd) {
        const int d = jd * 16 + l16;
        Oh[(size_t)(b * S_LEN + s) * D_MODEL + h * DEPTH + d] =
            (bf16)(o_acc[qs][jd][r] * inv);
      }
    }
  }
}

// ---------------------------------------------------------------- launch
extern "C" void kernel_launch(void* const* d_in, const int* in_sizes, int n_in,
                              void* d_out, int out_size, void* d_ws, size_t ws_size,
                              hipStream_t stream)
{
  const void* q    = d_in[0];
  const void* k    = d_in[1];
  const void* v    = d_in[2];
  const int*  mask = (const int*)d_in[3];
  const void* wq   = d_in[4];
  const void* bq   = d_in[5];
  const void* wk   = d_in[6];
  const void* bk   = d_in[7];
  const void* wv   = d_in[8];
  const void* bv   = d_in[9];
  const void* wo   = d_in[10];
  const void* bo   = d_in[11];

  char* ws = (char*)d_ws;
  const size_t MB = 1u << 20;
  bf16* Qh  = (bf16*)(ws + 0 * MB);    // [b,h,s,d]   8 MB (pre-scaled)
  bf16* Kc  = (bf16*)(ws + 8 * MB);    // [b,h,j,d]   8 MB compact
  bf16* Vc  = (bf16*)(ws + 16 * MB);   // [b,h,d,j]   8 MB compact
  bf16* Oh  = (bf16*)(ws + 24 * MB);   // [b,s,(h d)] 8 MB
  bf16* wqT = (bf16*)(ws + 32 * MB);
  bf16* wkT = (bf16*)(ws + 34 * MB);
  bf16* wvT = (bf16*)(ws + 36 * MB);
  bf16* woT = (bf16*)(ws + 38 * MB);
  bf16* bqb = (bf16*)(ws + 40 * MB);
  bf16* bkb = (bf16*)(ws + 40 * MB + 4096);
  bf16* bvb = (bf16*)(ws + 40 * MB + 8192);
  bf16* bob = (bf16*)(ws + 40 * MB + 12288);
  int*  flag = (int*)(ws + 40 * MB + 32768);
  int*  cpos = (int*)(ws + 40 * MB + 65536);           // 16 KB
  int*  nb   = (int*)(ws + 40 * MB + 65536 + 16384);   // 8 B
  bf16* qb  = (bf16*)(ws + 41 * MB);   // f32-conversion buffers (flag==0 only)
  bf16* kb_ = (bf16*)(ws + 49 * MB);
  bf16* vb_ = (bf16*)(ws + 57 * MB);

  setup<<<10246, 256, 0, stream>>>(
      q, k, v, mask, wq, wk, wv, wo, bq, bk, bv, bo,
      wqT, wkT, wvT, woT, bqb, bkb, bvb, bob,
      qb, kb_, vb_, cpos, nb, flag);

  GArgs gq{qb,  q,  wqT, bqb, Qh, nullptr, 1};
  GArgs gk{kb_, k,  wkT, bkb, Kc, cpos,    3};
  GArgs gv{vb_, v,  wvT, bvb, Vc, cpos,    2};
  gemm_qkv<<<dim3(8, 32, 3), 256, 0, stream>>>(gq, gk, gv, flag);

  attn<<<dim3(16, 32), 256, 0, stream>>>(Qh, Kc, Vc, nb, Oh);

  GArgs go{Oh, Oh, woT, bob, d_out, nullptr, 0};
  gemm_out<<<dim3(8, 32), 256, 0, stream>>>(go, flag);
}